// Round 4
// baseline (895.966 us; speedup 1.0000x reference)
//
#include <hip/hip_runtime.h>
#include <hip/hip_bf16.h>
#include <math.h>

#define F_IN   128
#define HID    128
#define NLAYER 3
#define NCLS   40
#define DCAT   512   // F_IN + NLAYER*HID

typedef short s16x8 __attribute__((ext_vector_type(8)));
typedef unsigned short u16x8 __attribute__((ext_vector_type(8)));
typedef unsigned short u16x4 __attribute__((ext_vector_type(4)));
typedef float f32x4 __attribute__((ext_vector_type(4)));

// ---------------- device helpers ----------------

static __device__ __forceinline__ float silu_f(float x) {
    return x / (1.f + __expf(-x));
}

static __device__ __forceinline__ unsigned short f2bf_rn(float f) {
    union { __hip_bfloat16 h; unsigned short u; } cv;
    cv.h = __float2bfloat16(f);
    return cv.u;
}

// ---------------- graph preprocessing ----------------

__global__ __launch_bounds__(256) void deg_init_kernel(int* deg, int N) {
    for (int i = blockIdx.x * blockDim.x + threadIdx.x; i < N; i += gridDim.x * blockDim.x)
        deg[i] = 1;  // self-loop
}

__global__ __launch_bounds__(256) void deg_count_kernel(const int* __restrict__ dst, int E, int* deg) {
    for (int i = blockIdx.x * blockDim.x + threadIdx.x; i < E; i += gridDim.x * blockDim.x)
        atomicAdd(&deg[dst[i]], 1);
}

__global__ __launch_bounds__(256) void dinv_kernel(const int* __restrict__ deg, float* dinv, int N) {
    for (int i = blockIdx.x * blockDim.x + threadIdx.x; i < N; i += gridDim.x * blockDim.x)
        dinv[i] = rsqrtf((float)deg[i]);
}

__global__ __launch_bounds__(1024) void scan_kernel(const int* __restrict__ deg, int* offs, int* cursor, int N) {
    __shared__ int part[1024];
    int t = threadIdx.x;
    int chunk = (N + 1023) >> 10;
    int begin = t * chunk;
    int end = begin + chunk; if (end > N) end = N;
    int s = 0;
    for (int i = begin; i < end; ++i) s += deg[i];
    part[t] = s;
    __syncthreads();
    for (int off = 1; off < 1024; off <<= 1) {
        int v = 0;
        if (t >= off) v = part[t - off];
        __syncthreads();
        if (t >= off) part[t] += v;
        __syncthreads();
    }
    int run = (t == 0) ? 0 : part[t - 1];
    for (int i = begin; i < end; ++i) {
        offs[i] = run; cursor[i] = run;
        run += deg[i];
    }
    if (t == 1023) offs[N] = run;
}

__global__ __launch_bounds__(256) void fill_kernel(const int* __restrict__ src, const int* __restrict__ dst,
                                                   int E, int N, int* cursor, int* __restrict__ csr) {
    int total = E + N;
    for (int i = blockIdx.x * blockDim.x + threadIdx.x; i < total; i += gridDim.x * blockDim.x) {
        if (i < E) {
            int d = dst[i];
            int p = atomicAdd(&cursor[d], 1);
            csr[p] = src[i];
        } else {
            int n = i - E;
            int p = atomicAdd(&cursor[n], 1);
            csr[p] = n;
        }
    }
}

// ---------------- weight packing (bf16, pre-swizzled, chunked K) -------------
// Chunk sequence per 128-feature group g: [silu(g), spline(8g)..spline(8g+7)],
// each chunk K=128. Row swizzle: u16 index k stored at k ^ ((o&7)<<3).
// conv: per layer 9 chunks of [o:128][k:128]
__global__ __launch_bounds__(256) void pack_conv_mfma(const float* __restrict__ bw,
                                                      const float* __restrict__ sw,
                                                      const float* __restrict__ sc,
                                                      unsigned short* __restrict__ wpk) {
    int total = NLAYER * 9 * 128 * 128;
    for (int idx = blockIdx.x * blockDim.x + threadIdx.x; idx < total; idx += gridDim.x * blockDim.x) {
        int kd = idx & 127;
        int o  = (idx >> 7) & 127;
        int cc = (idx >> 14) % 9;
        int l  = idx / (9 << 14);
        int k = kd ^ ((o & 7) << 3);   // logical k
        float v;
        if (cc == 0) {
            int f = k;
            v = bw[(l * 128 + o) * 128 + f];
        } else {
            int f = (cc - 1) * 16 + (k >> 3);
            int j = k & 7;
            int base = (l * 128 + o) * 128 + f;
            v = sw[base * 8 + j] * sc[base];
        }
        wpk[idx] = f2bf_rn(v);
    }
}

// out: 36 chunks of [o:64][k:128]; group g = cc/9, r = cc%9
__global__ __launch_bounds__(256) void pack_out_mfma(const float* __restrict__ bw,
                                                     const float* __restrict__ sw,
                                                     const float* __restrict__ sc,
                                                     unsigned short* __restrict__ wpk) {
    int total = 36 * 64 * 128;
    for (int idx = blockIdx.x * blockDim.x + threadIdx.x; idx < total; idx += gridDim.x * blockDim.x) {
        int kd = idx & 127;
        int o  = (idx >> 7) & 63;
        int cc = idx >> 13;
        int g = cc / 9, r = cc % 9;
        int k = kd ^ ((o & 7) << 3);
        float v = 0.f;
        if (o < NCLS) {
            if (r == 0) {
                int f = g * 128 + k;
                v = bw[o * DCAT + f];
            } else {
                int f = (g * 8 + r - 1) * 16 + (k >> 3);
                int j = k & 7;
                int base = o * DCAT + f;
                v = sw[base * 8 + j] * sc[base];
            }
        }
        wpk[idx] = f2bf_rn(v);
    }
}

// ---------------- misc data movement ----------------

__global__ __launch_bounds__(256) void copyx_kernel(const float* __restrict__ x, float* __restrict__ xc, int N) {
    int total = N * F_IN;
    for (int idx = blockIdx.x * blockDim.x + threadIdx.x; idx < total; idx += gridDim.x * blockDim.x) {
        int n = idx >> 7, f = idx & 127;
        xc[(size_t)n * DCAT + f] = x[idx];
    }
}

__global__ __launch_bounds__(512) void affine_init_kernel(float* scA, float* shA) {
    int i = threadIdx.x;
    scA[i] = 1.f; shA[i] = 0.f;
}

// ---------------- fused KAN GEMM (bf16 MFMA 16x16x32, chunked K=128) ---------
// Block: 256 threads (4 waves 2x2), tile 128 nodes x OUTT outs.
// NCH = NGRP*9 chunks; LDS rows 256B with XOR swizzle byte ^= ((row&7)<<4).
template<int OUTT, int NCH, bool MASK40>
__global__ __launch_bounds__(256, 2) void kan_mfma_kernel(
    const float* __restrict__ xc, int in_off,
    const float* __restrict__ scA, const float* __restrict__ shA,
    const unsigned short* __restrict__ wpk,
    float* __restrict__ outp, int out_ld, int N) {

    constexpr int CT = OUTT / 32;            // col frag tiles per wave
    constexpr int WITERS = OUTT / 16;        // float4 staging iters for W (OUTT*256/16/256)
    __shared__ __align__(16) char lds[32768 + OUTT * 256];
    char* lds_phi = lds;
    char* lds_w = lds + 32768;

    const int tid = threadIdx.x;
    const int lane = tid & 63;
    const int wave = tid >> 6;
    const int wr = wave >> 1, wc = wave & 1;
    const int l15 = lane & 15, lg = lane >> 4;
    const int nblk = blockIdx.x * 128;

    const float g0 = -1.f - 3.f * 0.4f;      // grid start: -1 - SPLINE_ORDER*h, h=2/5
    const float invh = 1.f / 0.4f;

    // spline staging decomposition: (fg = tid&3 : 4 features), nodes {n0, n0+64}
    const int fg = tid & 3;
    const int n0 = tid >> 2;                 // 0..63
    // silu staging decomposition: (fgS = tid&31 : 4 features), rows nS + 8*it
    const int fgS = tid & 31;
    const int nS = tid >> 5;                 // 0..7

    f32x4 acc[4][CT];
#pragma unroll
    for (int r = 0; r < 4; ++r)
#pragma unroll
        for (int c = 0; c < CT; ++c) acc[r][c] = (f32x4)0.f;

    for (int cc = 0; cc < NCH; ++cc) {
        const int g = cc / 9, r9 = cc % 9;
        const bool is_sil = (r9 == 0);

        // issue W staging loads (global -> regs) first: hidden under phi VALU
        const float4* wg = (const float4*)(wpk + (size_t)cc * OUTT * 128);
        float4 wreg[WITERS];
#pragma unroll
        for (int i = 0; i < WITERS; ++i) wreg[i] = wg[tid + i * 256];

        // compute phi into registers
        u16x4 psil[16];
        u16x8 psp[2][4];
        if (is_sil) {
            const int ab = in_off + g * 128 + fgS * 4;
            float4 scq = *(const float4*)(scA + ab);
            float4 shq = *(const float4*)(shA + ab);
            float scr[4] = {scq.x, scq.y, scq.z, scq.w};
            float shr[4] = {shq.x, shq.y, shq.z, shq.w};
#pragma unroll
            for (int it = 0; it < 16; ++it) {
                int n = nS + it * 8;
                int gn = nblk + n;
                float4 xq = (gn < N) ? *(const float4*)(xc + (size_t)gn * DCAT + ab)
                                     : (float4){0.f, 0.f, 0.f, 0.f};
                float xi[4] = {xq.x, xq.y, xq.z, xq.w};
#pragma unroll
                for (int e = 0; e < 4; ++e) {
                    float y = fmaf(xi[e], scr[e], shr[e]);
                    psil[it][e] = f2bf_rn(silu_f(y));
                }
            }
        } else {
            const int f0 = in_off + (g * 8 + r9 - 1) * 16 + fg * 4;
            float4 scq = *(const float4*)(scA + f0);
            float4 shq = *(const float4*)(shA + f0);
            float scr[4] = {scq.x, scq.y, scq.z, scq.w};
            float shr[4] = {shq.x, shq.y, shq.z, shq.w};
#pragma unroll
            for (int gidx = 0; gidx < 2; ++gidx) {
                int gn = nblk + n0 + gidx * 64;
                float4 xq = (gn < N) ? *(const float4*)(xc + (size_t)gn * DCAT + f0)
                                     : (float4){0.f, 0.f, 0.f, 0.f};
                float xi[4] = {xq.x, xq.y, xq.z, xq.w};
#pragma unroll
                for (int fl = 0; fl < 4; ++fl) {
                    float y = fmaf(xi[fl], scr[fl], shr[fl]);
                    float t = (y - g0) * invh;
                    float cf = floorf(t);
                    int c = (int)cf;
                    float u = t - cf;
                    float um = 1.f - u;
                    float u2 = u * u;
                    float um2 = um * um;
                    float w0 = um2 * um * (1.f / 6.f);
                    float w3 = u2 * u * (1.f / 6.f);
                    float w1 = fmaf(fmaf(0.5f, u, -1.f), u2, 2.f / 3.f);
                    float w2 = fmaf(fmaf(-0.5f, u, 0.5f), u2, fmaf(0.5f, u, 1.f / 6.f));
                    bool e[11];
#pragma unroll
                    for (int v = 0; v < 11; ++v) e[v] = (c == v);
#pragma unroll
                    for (int s = 0; s < 8; ++s) {
                        float val = 0.f;
                        val = e[s] ? w3 : val;
                        val = e[s + 1] ? w2 : val;
                        val = e[s + 2] ? w1 : val;
                        val = e[s + 3] ? w0 : val;
                        psp[gidx][fl][s] = f2bf_rn(val);
                    }
                }
            }
        }

        __syncthreads();   // previous chunk's MFMA reads complete

        // write phi + W to LDS
        if (is_sil) {
#pragma unroll
            for (int it = 0; it < 16; ++it) {
                int n = nS + it * 8;
                int byte = n * 256 + ((fgS * 8) ^ ((n & 7) << 4));
                *(u16x4*)(lds_phi + byte) = psil[it];
            }
        } else {
#pragma unroll
            for (int gidx = 0; gidx < 2; ++gidx) {
                int n = n0 + gidx * 64;
                int swz = (n & 7) << 4;
#pragma unroll
                for (int i = 0; i < 4; ++i) {
                    int byte = n * 256 + ((fg * 64 + i * 16) ^ swz);
                    *(u16x8*)(lds_phi + byte) = psp[gidx][i];
                }
            }
        }
        {
            float4* wl = (float4*)lds_w;
#pragma unroll
            for (int i = 0; i < WITERS; ++i) wl[tid + i * 256] = wreg[i];
        }

        __syncthreads();

        // MFMA over 4 k-steps of 32
#pragma unroll
        for (int kk = 0; kk < 4; ++kk) {
            const int kb = kk * 64 + lg * 16;
            s16x8 af[4];
#pragma unroll
            for (int r = 0; r < 4; ++r) {
                int n = wr * 64 + r * 16 + l15;
                af[r] = *(const s16x8*)(lds_phi + n * 256 + (kb ^ ((n & 7) << 4)));
            }
#pragma unroll
            for (int c = 0; c < CT; ++c) {
                int o = wc * (OUTT / 2) + c * 16 + l15;
                s16x8 bfr = *(const s16x8*)(lds_w + o * 256 + (kb ^ ((o & 7) << 4)));
#pragma unroll
                for (int r = 0; r < 4; ++r)
                    acc[r][c] = __builtin_amdgcn_mfma_f32_16x16x32_bf16(af[r], bfr, acc[r][c], 0, 0, 0);
            }
        }
    }

    // epilogue: C row=node (lg*4+q within 16-tile), col=out (l15)
#pragma unroll
    for (int r = 0; r < 4; ++r) {
        int nb = nblk + wr * 64 + r * 16 + lg * 4;
#pragma unroll
        for (int c = 0; c < CT; ++c) {
            int o = wc * (OUTT / 2) + c * 16 + l15;
            if (!MASK40 || o < NCLS) {
#pragma unroll
                for (int q = 0; q < 4; ++q) {
                    int n = nb + q;
                    if (n < N) outp[(size_t)n * out_ld + o] = acc[r][c][q];
                }
            }
        }
    }
}

// ---------------- aggregation (one wave per node, float2 lanes) --------------
__global__ __launch_bounds__(256) void agg_kernel(const float* __restrict__ h,
                                                  const float* __restrict__ dinv,
                                                  const int* __restrict__ offs,
                                                  const int* __restrict__ csr,
                                                  const float* __restrict__ bias,
                                                  float* __restrict__ xc, int out_off, int N) {
    int n = blockIdx.x * 4 + (threadIdx.x >> 6);
    if (n >= N) return;
    int lane = threadIdx.x & 63;
    int s = offs[n], e = offs[n + 1];
    float a0 = 0.f, a1 = 0.f;
    for (int i = s; i < e; ++i) {
        int v = csr[i];
        float dv = dinv[v];
        float2 hv = *(const float2*)(h + (size_t)v * HID + lane * 2);
        a0 = fmaf(hv.x, dv, a0);
        a1 = fmaf(hv.y, dv, a1);
    }
    float dn = dinv[n];
    float2 bv = *(const float2*)(bias + lane * 2);
    float2 res = {a0 * dn + bv.x, a1 * dn + bv.y};
    *(float2*)(xc + (size_t)n * DCAT + out_off + lane * 2) = res;
}

// ---------------- batchnorm stats + deferred affine ----------------
__global__ __launch_bounds__(128) void bn_stats_kernel(const float* __restrict__ xc, int off, int N,
                                                       float* __restrict__ bnsum, float* __restrict__ bnsq) {
    int f = threadIdx.x;
    float s = 0.f, q = 0.f;
    for (int n = blockIdx.x; n < N; n += gridDim.x) {
        float v = xc[(size_t)n * DCAT + off + f];
        s += v;
        q += v * v;
    }
    atomicAdd(&bnsum[f], s);
    atomicAdd(&bnsq[f], q);
}

__global__ __launch_bounds__(128) void bn_affine_kernel(const float* __restrict__ bnsum,
                                                        const float* __restrict__ bnsq,
                                                        const float* __restrict__ gamma,
                                                        const float* __restrict__ beta,
                                                        float* scA, float* shA, int seg_off, float invN) {
    int f = threadIdx.x;
    float mu = bnsum[f] * invN;
    float var = bnsq[f] * invN - mu * mu;
    float rs = rsqrtf(var + 1e-5f);
    float s = gamma[f] * rs;
    scA[seg_off + f] = s;
    shA[seg_off + f] = fmaf(-mu, s, beta[f]);
}

// ---------------- log_softmax (thread per node) ----------------
__global__ __launch_bounds__(256) void logsoftmax_kernel(float* __restrict__ out, int N) {
    for (int n = blockIdx.x * blockDim.x + threadIdx.x; n < N; n += gridDim.x * blockDim.x) {
        float* row = out + (size_t)n * NCLS;
        float m = -1e30f;
#pragma unroll
        for (int j = 0; j < NCLS; ++j) m = fmaxf(m, row[j]);
        float s = 0.f;
#pragma unroll
        for (int j = 0; j < NCLS; ++j) s += __expf(row[j] - m);
        float lse = m + __logf(s);
#pragma unroll
        for (int j = 0; j < NCLS; ++j) row[j] = row[j] - lse;
    }
}

// ---------------- launch ----------------

extern "C" void kernel_launch(void* const* d_in, const int* in_sizes, int n_in,
                              void* d_out, int out_size, void* d_ws, size_t ws_size,
                              hipStream_t stream) {
    const float* x            = (const float*)d_in[0];
    const int*   eidx         = (const int*)d_in[1];
    const float* conv_base_w  = (const float*)d_in[3];
    const float* conv_spline_w= (const float*)d_in[4];
    const float* conv_scaler  = (const float*)d_in[5];
    const float* conv_bias    = (const float*)d_in[6];
    const float* bn_gamma     = (const float*)d_in[7];
    const float* bn_beta      = (const float*)d_in[8];
    const float* out_base_w   = (const float*)d_in[10];
    const float* out_spline_w = (const float*)d_in[11];
    const float* out_scaler   = (const float*)d_in[12];
    float* out = (float*)d_out;

    int N = in_sizes[0] / F_IN;
    int E = in_sizes[1] / 2;
    const int* esrc = eidx;
    const int* edst = eidx + E;

    char* p = (char*)d_ws;
    auto carve = [&](size_t bytes) {
        char* r = p;
        p += (bytes + 255) & ~(size_t)255;
        return r;
    };
    float* xc   = (float*)carve((size_t)N * DCAT * 4);
    float* htmp = (float*)carve((size_t)N * HID * 4);
    float* dinv = (float*)carve((size_t)N * 4);
    float* bn   = (float*)carve((size_t)NLAYER * 2 * HID * 4);
    float* scA  = (float*)carve((size_t)DCAT * 4);
    float* shA  = (float*)carve((size_t)DCAT * 4);
    unsigned short* wpkc = (unsigned short*)carve((size_t)NLAYER * 9 * 128 * 128 * 2);
    unsigned short* wpko = (unsigned short*)carve((size_t)36 * 64 * 128 * 2);
    int* deg    = (int*)carve((size_t)N * 4);
    int* offs   = (int*)carve((size_t)(N + 1) * 4);
    int* cursor = (int*)carve((size_t)(N + 1) * 4);
    int* csr    = (int*)carve((size_t)(E + N) * 4);

    hipMemsetAsync(bn, 0, NLAYER * 2 * HID * 4, stream);

    // graph preprocessing
    deg_init_kernel<<<512, 256, 0, stream>>>(deg, N);
    deg_count_kernel<<<1024, 256, 0, stream>>>(edst, E, deg);
    dinv_kernel<<<512, 256, 0, stream>>>(deg, dinv, N);
    scan_kernel<<<1, 1024, 0, stream>>>(deg, offs, cursor, N);
    fill_kernel<<<1024, 256, 0, stream>>>(esrc, edst, E, N, cursor, csr);

    // weight packing + x copy + affine init
    pack_conv_mfma<<<1024, 256, 0, stream>>>(conv_base_w, conv_spline_w, conv_scaler, wpkc);
    pack_out_mfma<<<1024, 256, 0, stream>>>(out_base_w, out_spline_w, out_scaler, wpko);
    copyx_kernel<<<2048, 256, 0, stream>>>(x, xc, N);
    affine_init_kernel<<<1, 512, 0, stream>>>(scA, shA);

    int blocks = (N + 127) / 128;
    float invN = 1.f / (float)N;
    for (int l = 0; l < NLAYER; ++l) {
        int in_off = l * HID;
        int out_off = (l + 1) * HID;
        const unsigned short* wl = wpkc + (size_t)l * 9 * 128 * 128;
        kan_mfma_kernel<128, 9, false><<<blocks, 256, 0, stream>>>(
            xc, in_off, scA, shA, wl, htmp, HID, N);
        agg_kernel<<<(N + 3) / 4, 256, 0, stream>>>(htmp, dinv, offs, csr, conv_bias + l * HID, xc, out_off, N);
        float* bnsum = bn + l * 2 * HID;
        float* bnsq  = bnsum + HID;
        bn_stats_kernel<<<256, 128, 0, stream>>>(xc, out_off, N, bnsum, bnsq);
        bn_affine_kernel<<<1, 128, 0, stream>>>(bnsum, bnsq, bn_gamma + l * HID, bn_beta + l * HID,
                                                scA, shA, out_off, invN);
    }

    kan_mfma_kernel<64, 36, true><<<blocks, 256, 0, stream>>>(
        xc, 0, scA, shA, wpko, out, NCLS, N);
    logsoftmax_kernel<<<(N + 255) / 256, 256, 0, stream>>>(out, N);
}

// Round 5
// 755.473 us; speedup vs baseline: 1.1860x; 1.1860x over previous
//
#include <hip/hip_runtime.h>
#include <hip/hip_bf16.h>
#include <math.h>

#define F_IN   128
#define HID    128
#define NLAYER 3
#define NCLS   40
#define DCAT   512   // F_IN + NLAYER*HID
#define OOUT   64    // padded out-layer cols

typedef short s16x8 __attribute__((ext_vector_type(8)));
typedef unsigned short u16x8 __attribute__((ext_vector_type(8)));
typedef float f32x4 __attribute__((ext_vector_type(4)));

// ---------------- device helpers ----------------

static __device__ __forceinline__ float silu_f(float x) {
    return x / (1.f + __expf(-x));
}

static __device__ __forceinline__ unsigned short f2bf_rn(float f) {
    union { __hip_bfloat16 h; unsigned short u; } cv;
    cv.h = __float2bfloat16(f);
    return cv.u;
}

static __device__ __forceinline__ void gload_lds16(const void* g, void* l) {
    __builtin_amdgcn_global_load_lds(
        (const __attribute__((address_space(1))) void*)g,
        (__attribute__((address_space(3))) void*)l, 16, 0, 0);
}

// ---------------- graph preprocessing ----------------

__global__ __launch_bounds__(256) void deg_init_kernel(int* deg, int N) {
    for (int i = blockIdx.x * blockDim.x + threadIdx.x; i < N; i += gridDim.x * blockDim.x)
        deg[i] = 1;  // self-loop
}

__global__ __launch_bounds__(256) void deg_count_kernel(const int* __restrict__ dst, int E, int* deg) {
    for (int i = blockIdx.x * blockDim.x + threadIdx.x; i < E; i += gridDim.x * blockDim.x)
        atomicAdd(&deg[dst[i]], 1);
}

__global__ __launch_bounds__(256) void dinv_kernel(const int* __restrict__ deg, float* dinv, int N) {
    for (int i = blockIdx.x * blockDim.x + threadIdx.x; i < N; i += gridDim.x * blockDim.x)
        dinv[i] = rsqrtf((float)deg[i]);
}

__global__ __launch_bounds__(1024) void scan_kernel(const int* __restrict__ deg, int* offs, int* cursor, int N) {
    __shared__ int part[1024];
    int t = threadIdx.x;
    int chunk = (N + 1023) >> 10;
    int begin = t * chunk;
    int end = begin + chunk; if (end > N) end = N;
    int s = 0;
    for (int i = begin; i < end; ++i) s += deg[i];
    part[t] = s;
    __syncthreads();
    for (int off = 1; off < 1024; off <<= 1) {
        int v = 0;
        if (t >= off) v = part[t - off];
        __syncthreads();
        if (t >= off) part[t] += v;
        __syncthreads();
    }
    int run = (t == 0) ? 0 : part[t - 1];
    for (int i = begin; i < end; ++i) {
        offs[i] = run; cursor[i] = run;
        run += deg[i];
    }
    if (t == 1023) offs[N] = run;
}

__global__ __launch_bounds__(256) void fill_kernel(const int* __restrict__ src, const int* __restrict__ dst,
                                                   int E, int N, int* cursor, int* __restrict__ csr) {
    int total = E + N;
    for (int i = blockIdx.x * blockDim.x + threadIdx.x; i < total; i += gridDim.x * blockDim.x) {
        if (i < E) {
            int d = dst[i];
            int p = atomicAdd(&cursor[d], 1);
            csr[p] = src[i];
        } else {
            int n = i - E;
            int p = atomicAdd(&cursor[n], 1);
            csr[p] = n;
        }
    }
}

// ---------------- weight packing (bf16, pre-swizzled, chunk order sp0..sp7,silu) ---
// Per chunk [o][kd] with kd = k ^ ((o&7)<<3).
// conv: [l][cc(9)][o(128)][kd(128)]
__global__ __launch_bounds__(256) void pack_conv_mfma(const float* __restrict__ bw,
                                                      const float* __restrict__ sw,
                                                      const float* __restrict__ sc,
                                                      unsigned short* __restrict__ wpk) {
    int total = NLAYER * 9 * 128 * 128;
    for (int idx = blockIdx.x * blockDim.x + threadIdx.x; idx < total; idx += gridDim.x * blockDim.x) {
        int kd = idx & 127;
        int o  = (idx >> 7) & 127;
        int cc = (idx >> 14) % 9;
        int l  = idx / (9 << 14);
        int k = kd ^ ((o & 7) << 3);   // logical k
        float v;
        if (cc == 8) {                 // silu chunk
            v = bw[(l * 128 + o) * 128 + k];
        } else {                       // spline chunk: 16 feats x 8 bases
            int f = cc * 16 + (k >> 3);
            int j = k & 7;
            int base = (l * 128 + o) * 128 + f;
            v = sw[base * 8 + j] * sc[base];
        }
        wpk[idx] = f2bf_rn(v);
    }
}

// out: [g(4)][cc(9)][o(64)][kd(128)], cols >= NCLS zeroed
__global__ __launch_bounds__(256) void pack_out_mfma(const float* __restrict__ bw,
                                                     const float* __restrict__ sw,
                                                     const float* __restrict__ sc,
                                                     unsigned short* __restrict__ wpk) {
    int total = 4 * 9 * 64 * 128;
    for (int idx = blockIdx.x * blockDim.x + threadIdx.x; idx < total; idx += gridDim.x * blockDim.x) {
        int kd = idx & 127;
        int o  = (idx >> 7) & 63;
        int cc = (idx >> 13) % 9;
        int g  = idx / (9 << 13);
        int k = kd ^ ((o & 7) << 3);
        float v = 0.f;
        if (o < NCLS) {
            if (cc == 8) {
                int f = g * 128 + k;
                v = bw[o * DCAT + f];
            } else {
                int f = g * 128 + cc * 16 + (k >> 3);
                int j = k & 7;
                int base = o * DCAT + f;
                v = sw[base * 8 + j] * sc[base];
            }
        }
        wpk[idx] = f2bf_rn(v);
    }
}

// ---------------- misc data movement ----------------

__global__ __launch_bounds__(256) void copyx_kernel(const float* __restrict__ x, float* __restrict__ xc, int N) {
    int total = N * F_IN;
    for (int idx = blockIdx.x * blockDim.x + threadIdx.x; idx < total; idx += gridDim.x * blockDim.x) {
        int n = idx >> 7, f = idx & 127;
        xc[(size_t)n * DCAT + f] = x[idx];
    }
}

__global__ __launch_bounds__(512) void affine_init_kernel(float* scA, float* shA) {
    int i = threadIdx.x;
    scA[i] = 1.f; shA[i] = 0.f;
}

// silu prep: pre-swizzled bf16 silu(affine(x)) for one 128-feature segment
__global__ __launch_bounds__(256) void silu_prep_kernel(const float* __restrict__ xc, int off,
                                                        const float* __restrict__ scA,
                                                        const float* __restrict__ shA,
                                                        unsigned short* __restrict__ silbuf, int N) {
    int total = N * 128;
    for (int idx = blockIdx.x * blockDim.x + threadIdx.x; idx < total; idx += gridDim.x * blockDim.x) {
        int n = idx >> 7, f = idx & 127;
        float y = fmaf(xc[(size_t)n * DCAT + off + f], scA[off + f], shA[off + f]);
        silbuf[(size_t)n * 128 + (f ^ ((n & 7) << 3))] = f2bf_rn(silu_f(y));
    }
}

// ---------------- fused KAN GEMM + out-layer partial (bf16 MFMA 16x16x32) ----
// Block: 256 threads (4 waves 2x2), tile 128 nodes.
// Chunks 0..7: spline (16 feats x 8 bases, K=128), chunk 8: silu (staged from silbuf).
// Conv branch (CONV): 128 cols -> htmp. Out branch: 64 cols -> out_acc (RMW, INIT for layer 0).
// LDS rows 256B, XOR swizzle byte ^= ((row&7)<<4); W pre-swizzled in global, linear LDS.
template<bool CONV, bool INIT>
__global__ __launch_bounds__(256, 2) void kan_fused_kernel(
    const float* __restrict__ xc, int in_off,
    const float* __restrict__ scA, const float* __restrict__ shA,
    const unsigned short* __restrict__ wconv,
    const unsigned short* __restrict__ wout,
    const unsigned short* __restrict__ silbuf,
    float* __restrict__ htmp,
    float* __restrict__ out_acc, int N) {

    constexpr int LDS_WC = CONV ? 32768 : 0;
    __shared__ __align__(16) char lds[32768 + LDS_WC + 16384];
    char* lds_phi = lds;
    char* lds_wc  = lds + 32768;
    char* lds_wo  = lds + 32768 + LDS_WC;

    const int tid = threadIdx.x;
    const int lane = tid & 63;
    const int wave = tid >> 6;
    const int wr = wave >> 1, wc = wave & 1;
    const int l15 = lane & 15, lg = lane >> 4;
    const int nblk = blockIdx.x * 128;

    const float g0 = -1.f - 3.f * 0.4f;
    const float invh = 1.f / 0.4f;

    // spline staging decomposition: (fg = tid&3 : 4 features), nodes {n0, n0+64}
    const int fg = tid & 3;
    const int n0 = tid >> 2;

    f32x4 accc[4][4];   // conv 128 cols
    f32x4 acco[4][2];   // out 64 cols
    if (CONV) {
#pragma unroll
        for (int r = 0; r < 4; ++r)
#pragma unroll
            for (int c = 0; c < 4; ++c) accc[r][c] = (f32x4)0.f;
    }
#pragma unroll
    for (int r = 0; r < 4; ++r)
#pragma unroll
        for (int c = 0; c < 2; ++c) acco[r][c] = (f32x4)0.f;

    float4 xq[2], scq, shq;
    auto ldx = [&](int cc) {
        int f0 = in_off + cc * 16 + fg * 4;
        scq = *(const float4*)(scA + f0);
        shq = *(const float4*)(shA + f0);
        int gn0 = nblk + n0, gn1 = gn0 + 64;
        xq[0] = (gn0 < N) ? *(const float4*)(xc + (size_t)gn0 * DCAT + f0) : (float4){0.f,0.f,0.f,0.f};
        xq[1] = (gn1 < N) ? *(const float4*)(xc + (size_t)gn1 * DCAT + f0) : (float4){0.f,0.f,0.f,0.f};
    };

    u16x8 pcur[2][4];
    auto phi_compute = [&]() {
#pragma unroll
        for (int g2 = 0; g2 < 2; ++g2) {
            float xi[4] = {xq[g2].x, xq[g2].y, xq[g2].z, xq[g2].w};
            float scr[4] = {scq.x, scq.y, scq.z, scq.w};
            float shr[4] = {shq.x, shq.y, shq.z, shq.w};
#pragma unroll
            for (int fl = 0; fl < 4; ++fl) {
                float y = fmaf(xi[fl], scr[fl], shr[fl]);
                float t = (y - g0) * invh;
                float cf = floorf(t);
                int c = (int)cf;
                float u = t - cf;
                float um = 1.f - u;
                float u2 = u * u;
                float um2 = um * um;
                float w0 = um2 * um * (1.f / 6.f);
                float w3 = u2 * u * (1.f / 6.f);
                float w1 = fmaf(fmaf(0.5f, u, -1.f), u2, 2.f / 3.f);
                float w2 = fmaf(fmaf(-0.5f, u, 0.5f), u2, fmaf(0.5f, u, 1.f / 6.f));
                bool e[11];
#pragma unroll
                for (int v = 0; v < 11; ++v) e[v] = (c == v);
#pragma unroll
                for (int s = 0; s < 8; ++s) {
                    float val = 0.f;
                    val = e[s] ? w3 : val;
                    val = e[s + 1] ? w2 : val;
                    val = e[s + 2] ? w1 : val;
                    val = e[s + 3] ? w0 : val;
                    pcur[g2][fl][s] = f2bf_rn(val);
                }
            }
        }
    };

    auto stage_w = [&](int cc) {
        if (CONV) {
            const unsigned short* wcsrc = wconv + (size_t)cc * 128 * 128;
#pragma unroll
            for (int i = 0; i < 8; ++i) {
                int e = tid + i * 256;
                gload_lds16(wcsrc + e * 8, lds_wc + e * 16);
            }
        }
        const unsigned short* wosrc = wout + (size_t)cc * 64 * 128;
#pragma unroll
        for (int i = 0; i < 4; ++i) {
            int e = tid + i * 256;
            gload_lds16(wosrc + e * 8, lds_wo + e * 16);
        }
    };

    auto mfma_phase = [&]() {
#pragma unroll
        for (int kk = 0; kk < 4; ++kk) {
            const int kb = kk * 64 + lg * 16;
            s16x8 af[4];
#pragma unroll
            for (int r = 0; r < 4; ++r) {
                int n = wr * 64 + r * 16 + l15;
                af[r] = *(const s16x8*)(lds_phi + n * 256 + (kb ^ ((n & 7) << 4)));
            }
            if (CONV) {
#pragma unroll
                for (int c = 0; c < 4; ++c) {
                    int o = wc * 64 + c * 16 + l15;
                    s16x8 b = *(const s16x8*)(lds_wc + o * 256 + (kb ^ ((o & 7) << 4)));
#pragma unroll
                    for (int r = 0; r < 4; ++r)
                        accc[r][c] = __builtin_amdgcn_mfma_f32_16x16x32_bf16(af[r], b, accc[r][c], 0, 0, 0);
                }
            }
#pragma unroll
            for (int c = 0; c < 2; ++c) {
                int o = wc * 32 + c * 16 + l15;
                s16x8 b = *(const s16x8*)(lds_wo + o * 256 + (kb ^ ((o & 7) << 4)));
#pragma unroll
                for (int r = 0; r < 4; ++r)
                    acco[r][c] = __builtin_amdgcn_mfma_f32_16x16x32_bf16(af[r], b, acco[r][c], 0, 0, 0);
            }
        }
    };

    // prologue: chunk 0 phi
    ldx(0);
    phi_compute();

    for (int cc = 0; cc < 8; ++cc) {
        __syncthreads();                   // prev MFMA done with LDS
        stage_w(cc);                       // async W -> LDS
        // write phi regs -> LDS
#pragma unroll
        for (int g2 = 0; g2 < 2; ++g2) {
            int n = n0 + g2 * 64;
            int swz = (n & 7) << 4;
#pragma unroll
            for (int i = 0; i < 4; ++i) {
                int byte = n * 256 + ((fg * 64 + i * 16) ^ swz);
                *(u16x8*)(lds_phi + byte) = pcur[g2][i];
            }
        }
        __syncthreads();                   // drains vmcnt+lds: W & phi ready
        if (cc < 7) ldx(cc + 1);           // issue next x loads (hidden by MFMA)
        mfma_phase();
        if (cc < 7) phi_compute();         // overlaps MFMA (separate pipes)
    }

    // silu chunk (cc=8): staged from pre-swizzled silbuf, zero VALU
    __syncthreads();
    stage_w(8);
    {
        const unsigned short* ssrc = silbuf + (size_t)nblk * 128;
#pragma unroll
        for (int i = 0; i < 8; ++i) {
            int e = tid + i * 256;
            gload_lds16(ssrc + e * 8, lds_phi + e * 16);
        }
    }
    __syncthreads();
    mfma_phase();

    // epilogue
#pragma unroll
    for (int r = 0; r < 4; ++r) {
        int nb = nblk + wr * 64 + r * 16 + lg * 4;
        if (CONV) {
#pragma unroll
            for (int c = 0; c < 4; ++c) {
                int o = wc * 64 + c * 16 + l15;
#pragma unroll
                for (int q = 0; q < 4; ++q) {
                    int n = nb + q;
                    if (n < N) htmp[(size_t)n * HID + o] = accc[r][c][q];
                }
            }
        }
#pragma unroll
        for (int c = 0; c < 2; ++c) {
            int o = wc * 32 + c * 16 + l15;
#pragma unroll
            for (int q = 0; q < 4; ++q) {
                int n = nb + q;
                if (n < N) {
                    size_t a = (size_t)n * OOUT + o;
                    float v = acco[r][c][q];
                    if (!INIT) v += out_acc[a];
                    out_acc[a] = v;
                }
            }
        }
    }
}

// ---------------- aggregation (one wave per node, float2 lanes) --------------
__global__ __launch_bounds__(256) void agg_kernel(const float* __restrict__ h,
                                                  const float* __restrict__ dinv,
                                                  const int* __restrict__ offs,
                                                  const int* __restrict__ csr,
                                                  const float* __restrict__ bias,
                                                  float* __restrict__ xc, int out_off, int N) {
    int n = blockIdx.x * 4 + (threadIdx.x >> 6);
    if (n >= N) return;
    int lane = threadIdx.x & 63;
    int s = offs[n], e = offs[n + 1];
    float a0 = 0.f, a1 = 0.f;
    for (int i = s; i < e; ++i) {
        int v = csr[i];
        float dv = dinv[v];
        float2 hv = *(const float2*)(h + (size_t)v * HID + lane * 2);
        a0 = fmaf(hv.x, dv, a0);
        a1 = fmaf(hv.y, dv, a1);
    }
    float dn = dinv[n];
    float2 bv = *(const float2*)(bias + lane * 2);
    float2 res = {a0 * dn + bv.x, a1 * dn + bv.y};
    *(float2*)(xc + (size_t)n * DCAT + out_off + lane * 2) = res;
}

// ---------------- batchnorm stats + deferred affine ----------------
__global__ __launch_bounds__(128) void bn_stats_kernel(const float* __restrict__ xc, int off, int N,
                                                       float* __restrict__ bnsum, float* __restrict__ bnsq) {
    int f = threadIdx.x;
    float s = 0.f, q = 0.f;
    for (int n = blockIdx.x; n < N; n += gridDim.x) {
        float v = xc[(size_t)n * DCAT + off + f];
        s += v;
        q += v * v;
    }
    atomicAdd(&bnsum[f], s);
    atomicAdd(&bnsq[f], q);
}

__global__ __launch_bounds__(128) void bn_affine_kernel(const float* __restrict__ bnsum,
                                                        const float* __restrict__ bnsq,
                                                        const float* __restrict__ gamma,
                                                        const float* __restrict__ beta,
                                                        float* scA, float* shA, int seg_off, float invN) {
    int f = threadIdx.x;
    float mu = bnsum[f] * invN;
    float var = bnsq[f] * invN - mu * mu;
    float rs = rsqrtf(var + 1e-5f);
    float s = gamma[f] * rs;
    scA[seg_off + f] = s;
    shA[seg_off + f] = fmaf(-mu, s, beta[f]);
}

// ---------------- log_softmax (thread per node; reads out_acc ld=64) ---------
__global__ __launch_bounds__(256) void logsoftmax_kernel(const float* __restrict__ oacc,
                                                         float* __restrict__ out, int N) {
    for (int n = blockIdx.x * blockDim.x + threadIdx.x; n < N; n += gridDim.x * blockDim.x) {
        const float* row = oacc + (size_t)n * OOUT;
        float m = -1e30f;
#pragma unroll
        for (int j = 0; j < NCLS; ++j) m = fmaxf(m, row[j]);
        float s = 0.f;
#pragma unroll
        for (int j = 0; j < NCLS; ++j) s += __expf(row[j] - m);
        float lse = m + __logf(s);
        float* orow = out + (size_t)n * NCLS;
#pragma unroll
        for (int j = 0; j < NCLS; ++j) orow[j] = row[j] - lse;
    }
}

// ---------------- launch ----------------

extern "C" void kernel_launch(void* const* d_in, const int* in_sizes, int n_in,
                              void* d_out, int out_size, void* d_ws, size_t ws_size,
                              hipStream_t stream) {
    const float* x            = (const float*)d_in[0];
    const int*   eidx         = (const int*)d_in[1];
    const float* conv_base_w  = (const float*)d_in[3];
    const float* conv_spline_w= (const float*)d_in[4];
    const float* conv_scaler  = (const float*)d_in[5];
    const float* conv_bias    = (const float*)d_in[6];
    const float* bn_gamma     = (const float*)d_in[7];
    const float* bn_beta      = (const float*)d_in[8];
    const float* out_base_w   = (const float*)d_in[10];
    const float* out_spline_w = (const float*)d_in[11];
    const float* out_scaler   = (const float*)d_in[12];
    float* out = (float*)d_out;

    int N = in_sizes[0] / F_IN;
    int E = in_sizes[1] / 2;
    const int* esrc = eidx;
    const int* edst = eidx + E;

    int blocks = (N + 127) / 128;
    int npad = blocks * 128;

    char* p = (char*)d_ws;
    auto carve = [&](size_t bytes) {
        char* r = p;
        p += (bytes + 255) & ~(size_t)255;
        return r;
    };
    float* xc   = (float*)carve((size_t)N * DCAT * 4);
    float* htmp = (float*)carve((size_t)npad * HID * 4);
    float* oacc = (float*)carve((size_t)npad * OOUT * 4);
    unsigned short* silbuf = (unsigned short*)carve((size_t)npad * 128 * 2);
    float* dinv = (float*)carve((size_t)N * 4);
    float* bn   = (float*)carve((size_t)NLAYER * 2 * HID * 4);
    float* scA  = (float*)carve((size_t)DCAT * 4);
    float* shA  = (float*)carve((size_t)DCAT * 4);
    unsigned short* wpkc = (unsigned short*)carve((size_t)NLAYER * 9 * 128 * 128 * 2);
    unsigned short* wpko = (unsigned short*)carve((size_t)4 * 9 * 64 * 128 * 2);
    int* deg    = (int*)carve((size_t)N * 4);
    int* offs   = (int*)carve((size_t)(N + 1) * 4);
    int* cursor = (int*)carve((size_t)(N + 1) * 4);
    int* csr    = (int*)carve((size_t)(E + N) * 4);

    hipMemsetAsync(bn, 0, NLAYER * 2 * HID * 4, stream);

    // graph preprocessing
    deg_init_kernel<<<512, 256, 0, stream>>>(deg, N);
    deg_count_kernel<<<1024, 256, 0, stream>>>(edst, E, deg);
    dinv_kernel<<<512, 256, 0, stream>>>(deg, dinv, N);
    scan_kernel<<<1, 1024, 0, stream>>>(deg, offs, cursor, N);
    fill_kernel<<<1024, 256, 0, stream>>>(esrc, edst, E, N, cursor, csr);

    // weight packing + x copy + affine init
    pack_conv_mfma<<<1024, 256, 0, stream>>>(conv_base_w, conv_spline_w, conv_scaler, wpkc);
    pack_out_mfma<<<1024, 256, 0, stream>>>(out_base_w, out_spline_w, out_scaler, wpko);
    copyx_kernel<<<2048, 256, 0, stream>>>(x, xc, N);
    affine_init_kernel<<<1, 512, 0, stream>>>(scA, shA);

    float invN = 1.f / (float)N;
    for (int l = 0; l < NLAYER; ++l) {
        int in_off = l * HID;
        int out_off = (l + 1) * HID;
        const unsigned short* wl = wpkc + (size_t)l * 9 * 128 * 128;
        const unsigned short* wo = wpko + (size_t)l * 9 * 64 * 128;
        silu_prep_kernel<<<1024, 256, 0, stream>>>(xc, in_off, scA, shA, silbuf, N);
        if (l == 0)
            kan_fused_kernel<true, true><<<blocks, 256, 0, stream>>>(
                xc, in_off, scA, shA, wl, wo, silbuf, htmp, oacc, N);
        else
            kan_fused_kernel<true, false><<<blocks, 256, 0, stream>>>(
                xc, in_off, scA, shA, wl, wo, silbuf, htmp, oacc, N);
        agg_kernel<<<(N + 3) / 4, 256, 0, stream>>>(htmp, dinv, offs, csr, conv_bias + l * HID, xc, out_off, N);
        float* bnsum = bn + l * 2 * HID;
        float* bnsq  = bnsum + HID;
        bn_stats_kernel<<<256, 128, 0, stream>>>(xc, out_off, N, bnsum, bnsq);
        bn_affine_kernel<<<1, 128, 0, stream>>>(bnsum, bnsq, bn_gamma + l * HID, bn_beta + l * HID,
                                                scA, shA, out_off, invN);
    }

    // segment 3 (final BN output) -> out partial
    silu_prep_kernel<<<1024, 256, 0, stream>>>(xc, 384, scA, shA, silbuf, N);
    kan_fused_kernel<false, false><<<blocks, 256, 0, stream>>>(
        xc, 384, scA, shA, nullptr, wpko + (size_t)3 * 9 * 64 * 128, silbuf, nullptr, oacc, N);

    logsoftmax_kernel<<<(N + 255) / 256, 256, 0, stream>>>(oacc, out, N);
}

// Round 6
// 657.360 us; speedup vs baseline: 1.3630x; 1.1493x over previous
//
#include <hip/hip_runtime.h>
#include <hip/hip_bf16.h>
#include <math.h>

#define F_IN   128
#define HID    128
#define NLAYER 3
#define NCLS   40
#define DCAT   512   // F_IN + NLAYER*HID
#define OOUT   64    // padded out-layer cols

typedef short s16x8 __attribute__((ext_vector_type(8)));
typedef unsigned short u16x8 __attribute__((ext_vector_type(8)));
typedef float f32x4 __attribute__((ext_vector_type(4)));

// ---------------- device helpers ----------------

static __device__ __forceinline__ float silu_f(float x) {
    return x / (1.f + __expf(-x));
}

static __device__ __forceinline__ unsigned short f2bf_rn(float f) {
    union { __hip_bfloat16 h; unsigned short u; } cv;
    cv.h = __float2bfloat16(f);
    return cv.u;
}

static __device__ __forceinline__ void gload_lds16(const void* g, void* l) {
    __builtin_amdgcn_global_load_lds(
        (const __attribute__((address_space(1))) void*)g,
        (__attribute__((address_space(3))) void*)l, 16, 0, 0);
}

// ---------------- graph preprocessing ----------------

__global__ __launch_bounds__(256) void deg_init_kernel(int* deg, int N) {
    for (int i = blockIdx.x * blockDim.x + threadIdx.x; i < N; i += gridDim.x * blockDim.x)
        deg[i] = 1;  // self-loop
}

__global__ __launch_bounds__(256) void deg_count_kernel(const int* __restrict__ dst, int E, int* deg) {
    for (int i = blockIdx.x * blockDim.x + threadIdx.x; i < E; i += gridDim.x * blockDim.x)
        atomicAdd(&deg[dst[i]], 1);
}

__global__ __launch_bounds__(256) void dinv_kernel(const int* __restrict__ deg, float* dinv, int N) {
    for (int i = blockIdx.x * blockDim.x + threadIdx.x; i < N; i += gridDim.x * blockDim.x)
        dinv[i] = rsqrtf((float)deg[i]);
}

// hierarchical scan: 1 elem/thread, 256/block
__global__ __launch_bounds__(256) void scan_reduce_kernel(const int* __restrict__ deg, int* __restrict__ bsum, int N) {
    __shared__ int sh[256];
    int t = threadIdx.x;
    int e = blockIdx.x * 256 + t;
    sh[t] = (e < N) ? deg[e] : 0;
    __syncthreads();
#pragma unroll
    for (int off = 128; off > 0; off >>= 1) {
        if (t < off) sh[t] += sh[t + off];
        __syncthreads();
    }
    if (t == 0) bsum[blockIdx.x] = sh[0];
}

__global__ __launch_bounds__(256) void scan_top_kernel(const int* __restrict__ bsum, int* __restrict__ bbase, int nsb) {
    __shared__ int sh[256];
    int t = threadIdx.x;
    int chunk = (nsb + 255) >> 8;
    int begin = t * chunk;
    int end = begin + chunk; if (end > nsb) end = nsb;
    int s = 0;
    for (int i = begin; i < end; ++i) s += bsum[i];
    sh[t] = s;
    __syncthreads();
#pragma unroll
    for (int off = 1; off < 256; off <<= 1) {
        int v = 0;
        if (t >= off) v = sh[t - off];
        __syncthreads();
        if (t >= off) sh[t] += v;
        __syncthreads();
    }
    int run = (t == 0) ? 0 : sh[t - 1];
    for (int i = begin; i < end; ++i) {
        bbase[i] = run;
        run += bsum[i];
    }
}

__global__ __launch_bounds__(256) void scan_write_kernel(const int* __restrict__ deg,
                                                         const int* __restrict__ bbase,
                                                         int* __restrict__ offs, int* __restrict__ cursor, int N) {
    __shared__ int sh[256];
    int t = threadIdx.x;
    int e = blockIdx.x * 256 + t;
    int d = (e < N) ? deg[e] : 0;
    sh[t] = d;
    __syncthreads();
#pragma unroll
    for (int off = 1; off < 256; off <<= 1) {
        int v = 0;
        if (t >= off) v = sh[t - off];
        __syncthreads();
        if (t >= off) sh[t] += v;
        __syncthreads();
    }
    int incl = sh[t] + bbase[blockIdx.x];
    int excl = incl - d;
    if (e < N) {
        offs[e] = excl;
        cursor[e] = excl;
        if (e == N - 1) offs[N] = incl;
    }
}

__global__ __launch_bounds__(256) void fill_kernel(const int* __restrict__ src, const int* __restrict__ dst,
                                                   int E, int N, int* cursor, int* __restrict__ csr) {
    int total = E + N;
    for (int i = blockIdx.x * blockDim.x + threadIdx.x; i < total; i += gridDim.x * blockDim.x) {
        if (i < E) {
            int d = dst[i];
            int p = atomicAdd(&cursor[d], 1);
            csr[p] = src[i];
        } else {
            int n = i - E;
            int p = atomicAdd(&cursor[n], 1);
            csr[p] = n;
        }
    }
}

// ---------------- weight packing (bf16, pre-swizzled, chunk order sp0..sp7,silu) ---
// Per chunk [o][kd] with kd = k ^ ((o&7)<<3).
// conv: [l][cc(9)][o(128)][kd(128)]
__global__ __launch_bounds__(256) void pack_conv_mfma(const float* __restrict__ bw,
                                                      const float* __restrict__ sw,
                                                      const float* __restrict__ sc,
                                                      unsigned short* __restrict__ wpk) {
    int total = NLAYER * 9 * 128 * 128;
    for (int idx = blockIdx.x * blockDim.x + threadIdx.x; idx < total; idx += gridDim.x * blockDim.x) {
        int kd = idx & 127;
        int o  = (idx >> 7) & 127;
        int cc = (idx >> 14) % 9;
        int l  = idx / (9 << 14);
        int k = kd ^ ((o & 7) << 3);   // logical k
        float v;
        if (cc == 8) {                 // silu chunk
            v = bw[(l * 128 + o) * 128 + k];
        } else {                       // spline chunk: 16 feats x 8 bases
            int f = cc * 16 + (k >> 3);
            int j = k & 7;
            int base = (l * 128 + o) * 128 + f;
            v = sw[base * 8 + j] * sc[base];
        }
        wpk[idx] = f2bf_rn(v);
    }
}

// out: [g(4)][cc(9)][o(64)][kd(128)], cols >= NCLS zeroed
__global__ __launch_bounds__(256) void pack_out_mfma(const float* __restrict__ bw,
                                                     const float* __restrict__ sw,
                                                     const float* __restrict__ sc,
                                                     unsigned short* __restrict__ wpk) {
    int total = 4 * 9 * 64 * 128;
    for (int idx = blockIdx.x * blockDim.x + threadIdx.x; idx < total; idx += gridDim.x * blockDim.x) {
        int kd = idx & 127;
        int o  = (idx >> 7) & 63;
        int cc = (idx >> 13) % 9;
        int g  = idx / (9 << 13);
        int k = kd ^ ((o & 7) << 3);
        float v = 0.f;
        if (o < NCLS) {
            if (cc == 8) {
                int f = g * 128 + k;
                v = bw[o * DCAT + f];
            } else {
                int f = g * 128 + cc * 16 + (k >> 3);
                int j = k & 7;
                int base = o * DCAT + f;
                v = sw[base * 8 + j] * sc[base];
            }
        }
        wpk[idx] = f2bf_rn(v);
    }
}

// ---------------- misc data movement ----------------

__global__ __launch_bounds__(256) void copyx_kernel(const float* __restrict__ x, float* __restrict__ xc, int N) {
    int total = N * F_IN;
    for (int idx = blockIdx.x * blockDim.x + threadIdx.x; idx < total; idx += gridDim.x * blockDim.x) {
        int n = idx >> 7, f = idx & 127;
        xc[(size_t)n * DCAT + f] = x[idx];
    }
}

__global__ __launch_bounds__(512) void affine_init_kernel(float* scA, float* shA) {
    int i = threadIdx.x;
    scA[i] = 1.f; shA[i] = 0.f;
}

// silu prep: pre-swizzled bf16 silu(affine(x)) for one 128-feature segment
__global__ __launch_bounds__(256) void silu_prep_kernel(const float* __restrict__ xc, int off,
                                                        const float* __restrict__ scA,
                                                        const float* __restrict__ shA,
                                                        unsigned short* __restrict__ silbuf, int N) {
    int total = N * 128;
    for (int idx = blockIdx.x * blockDim.x + threadIdx.x; idx < total; idx += gridDim.x * blockDim.x) {
        int n = idx >> 7, f = idx & 127;
        float y = fmaf(xc[(size_t)n * DCAT + off + f], scA[off + f], shA[off + f]);
        silbuf[(size_t)n * 128 + (f ^ ((n & 7) << 3))] = f2bf_rn(silu_f(y));
    }
}

// ---------------- fused KAN GEMM + out-layer partial (bf16 MFMA 16x16x32) ----
// Block: 256 threads (4 waves 2x2), tile 128 nodes.
// Chunks 0..7: spline (16 feats x 8 bases, K=128), chunk 8: silu (staged from silbuf).
// Conv branch (CONV): 128 cols -> htmp. Out branch: 64 cols -> out_acc (RMW, INIT for layer 0).
// LDS rows 256B, XOR swizzle byte ^= ((row&7)<<4); W pre-swizzled in global, linear LDS.
template<bool CONV, bool INIT>
__global__ __launch_bounds__(256, 2) void kan_fused_kernel(
    const float* __restrict__ xc, int in_off,
    const float* __restrict__ scA, const float* __restrict__ shA,
    const unsigned short* __restrict__ wconv,
    const unsigned short* __restrict__ wout,
    const unsigned short* __restrict__ silbuf,
    float* __restrict__ htmp,
    float* __restrict__ out_acc, int N) {

    constexpr int LDS_WC = CONV ? 32768 : 0;
    __shared__ __align__(16) char lds[32768 + LDS_WC + 16384];
    char* lds_phi = lds;
    char* lds_wc  = lds + 32768;
    char* lds_wo  = lds + 32768 + LDS_WC;

    const int tid = threadIdx.x;
    const int lane = tid & 63;
    const int wave = tid >> 6;
    const int wr = wave >> 1, wc = wave & 1;
    const int l15 = lane & 15, lg = lane >> 4;
    const int nblk = blockIdx.x * 128;

    const float g0 = -1.f - 3.f * 0.4f;
    const float invh = 1.f / 0.4f;

    // spline staging decomposition: (fg = tid&3 : 4 features), nodes {n0, n0+64}
    const int fg = tid & 3;
    const int n0 = tid >> 2;

    f32x4 accc[4][4];   // conv 128 cols
    f32x4 acco[4][2];   // out 64 cols
    if (CONV) {
#pragma unroll
        for (int r = 0; r < 4; ++r)
#pragma unroll
            for (int c = 0; c < 4; ++c) accc[r][c] = (f32x4)0.f;
    }
#pragma unroll
    for (int r = 0; r < 4; ++r)
#pragma unroll
        for (int c = 0; c < 2; ++c) acco[r][c] = (f32x4)0.f;

    float4 xq[2], scq, shq;
    auto ldx = [&](int cc) {
        int f0 = in_off + cc * 16 + fg * 4;
        scq = *(const float4*)(scA + f0);
        shq = *(const float4*)(shA + f0);
        int gn0 = nblk + n0, gn1 = gn0 + 64;
        xq[0] = (gn0 < N) ? *(const float4*)(xc + (size_t)gn0 * DCAT + f0) : (float4){0.f,0.f,0.f,0.f};
        xq[1] = (gn1 < N) ? *(const float4*)(xc + (size_t)gn1 * DCAT + f0) : (float4){0.f,0.f,0.f,0.f};
    };

    u16x8 pcur[2][4];
    auto phi_compute = [&]() {
#pragma unroll
        for (int g2 = 0; g2 < 2; ++g2) {
            float xi[4] = {xq[g2].x, xq[g2].y, xq[g2].z, xq[g2].w};
            float scr[4] = {scq.x, scq.y, scq.z, scq.w};
            float shr[4] = {shq.x, shq.y, shq.z, shq.w};
#pragma unroll
            for (int fl = 0; fl < 4; ++fl) {
                float y = fmaf(xi[fl], scr[fl], shr[fl]);
                float t = (y - g0) * invh;
                float cf = floorf(t);
                int c = (int)cf;
                float u = t - cf;
                float um = 1.f - u;
                float u2 = u * u;
                float um2 = um * um;
                float w0 = um2 * um * (1.f / 6.f);
                float w3 = u2 * u * (1.f / 6.f);
                float w1 = fmaf(fmaf(0.5f, u, -1.f), u2, 2.f / 3.f);
                float w2 = fmaf(fmaf(-0.5f, u, 0.5f), u2, fmaf(0.5f, u, 1.f / 6.f));
                bool e[11];
#pragma unroll
                for (int v = 0; v < 11; ++v) e[v] = (c == v);
#pragma unroll
                for (int s = 0; s < 8; ++s) {
                    float val = 0.f;
                    val = e[s] ? w3 : val;
                    val = e[s + 1] ? w2 : val;
                    val = e[s + 2] ? w1 : val;
                    val = e[s + 3] ? w0 : val;
                    pcur[g2][fl][s] = f2bf_rn(val);
                }
            }
        }
    };

    auto stage_w = [&](int cc) {
        if (CONV) {
            const unsigned short* wcsrc = wconv + (size_t)cc * 128 * 128;
#pragma unroll
            for (int i = 0; i < 8; ++i) {
                int e = tid + i * 256;
                gload_lds16(wcsrc + e * 8, lds_wc + e * 16);
            }
        }
        const unsigned short* wosrc = wout + (size_t)cc * 64 * 128;
#pragma unroll
        for (int i = 0; i < 4; ++i) {
            int e = tid + i * 256;
            gload_lds16(wosrc + e * 8, lds_wo + e * 16);
        }
    };

    auto mfma_phase = [&]() {
#pragma unroll
        for (int kk = 0; kk < 4; ++kk) {
            const int kb = kk * 64 + lg * 16;
            s16x8 af[4];
#pragma unroll
            for (int r = 0; r < 4; ++r) {
                int n = wr * 64 + r * 16 + l15;
                af[r] = *(const s16x8*)(lds_phi + n * 256 + (kb ^ ((n & 7) << 4)));
            }
            if (CONV) {
#pragma unroll
                for (int c = 0; c < 4; ++c) {
                    int o = wc * 64 + c * 16 + l15;
                    s16x8 b = *(const s16x8*)(lds_wc + o * 256 + (kb ^ ((o & 7) << 4)));
#pragma unroll
                    for (int r = 0; r < 4; ++r)
                        accc[r][c] = __builtin_amdgcn_mfma_f32_16x16x32_bf16(af[r], b, accc[r][c], 0, 0, 0);
                }
            }
#pragma unroll
            for (int c = 0; c < 2; ++c) {
                int o = wc * 32 + c * 16 + l15;
                s16x8 b = *(const s16x8*)(lds_wo + o * 256 + (kb ^ ((o & 7) << 4)));
#pragma unroll
                for (int r = 0; r < 4; ++r)
                    acco[r][c] = __builtin_amdgcn_mfma_f32_16x16x32_bf16(af[r], b, acco[r][c], 0, 0, 0);
            }
        }
    };

    // prologue: chunk 0 phi
    ldx(0);
    phi_compute();

    for (int cc = 0; cc < 8; ++cc) {
        __syncthreads();                   // prev MFMA done with LDS
        stage_w(cc);                       // async W -> LDS
        // write phi regs -> LDS
#pragma unroll
        for (int g2 = 0; g2 < 2; ++g2) {
            int n = n0 + g2 * 64;
            int swz = (n & 7) << 4;
#pragma unroll
            for (int i = 0; i < 4; ++i) {
                int byte = n * 256 + ((fg * 64 + i * 16) ^ swz);
                *(u16x8*)(lds_phi + byte) = pcur[g2][i];
            }
        }
        __syncthreads();                   // drains vmcnt+lds: W & phi ready
        if (cc < 7) ldx(cc + 1);           // issue next x loads (hidden by MFMA)
        mfma_phase();
        if (cc < 7) phi_compute();         // overlaps MFMA (separate pipes)
    }

    // silu chunk (cc=8): staged from pre-swizzled silbuf, zero VALU
    __syncthreads();
    stage_w(8);
    {
        const unsigned short* ssrc = silbuf + (size_t)nblk * 128;
#pragma unroll
        for (int i = 0; i < 8; ++i) {
            int e = tid + i * 256;
            gload_lds16(ssrc + e * 8, lds_phi + e * 16);
        }
    }
    __syncthreads();
    mfma_phase();

    // epilogue
#pragma unroll
    for (int r = 0; r < 4; ++r) {
        int nb = nblk + wr * 64 + r * 16 + lg * 4;
        if (CONV) {
#pragma unroll
            for (int c = 0; c < 4; ++c) {
                int o = wc * 64 + c * 16 + l15;
#pragma unroll
                for (int q = 0; q < 4; ++q) {
                    int n = nb + q;
                    if (n < N) htmp[(size_t)n * HID + o] = accc[r][c][q];
                }
            }
        }
#pragma unroll
        for (int c = 0; c < 2; ++c) {
            int o = wc * 32 + c * 16 + l15;
#pragma unroll
            for (int q = 0; q < 4; ++q) {
                int n = nb + q;
                if (n < N) {
                    size_t a = (size_t)n * OOUT + o;
                    float v = acco[r][c][q];
                    if (!INIT) v += out_acc[a];
                    out_acc[a] = v;
                }
            }
        }
    }
}

// ---------------- aggregation (one wave per node, float2 lanes) --------------
__global__ __launch_bounds__(256) void agg_kernel(const float* __restrict__ h,
                                                  const float* __restrict__ dinv,
                                                  const int* __restrict__ offs,
                                                  const int* __restrict__ csr,
                                                  const float* __restrict__ bias,
                                                  float* __restrict__ xc, int out_off, int N) {
    int n = blockIdx.x * 4 + (threadIdx.x >> 6);
    if (n >= N) return;
    int lane = threadIdx.x & 63;
    int s = offs[n], e = offs[n + 1];
    float a0 = 0.f, a1 = 0.f;
    for (int i = s; i < e; ++i) {
        int v = csr[i];
        float dv = dinv[v];
        float2 hv = *(const float2*)(h + (size_t)v * HID + lane * 2);
        a0 = fmaf(hv.x, dv, a0);
        a1 = fmaf(hv.y, dv, a1);
    }
    float dn = dinv[n];
    float2 bv = *(const float2*)(bias + lane * 2);
    float2 res = {a0 * dn + bv.x, a1 * dn + bv.y};
    *(float2*)(xc + (size_t)n * DCAT + out_off + lane * 2) = res;
}

// ---------------- batchnorm stats + deferred affine ----------------
__global__ __launch_bounds__(128) void bn_stats_kernel(const float* __restrict__ xc, int off, int N,
                                                       float* __restrict__ bnsum, float* __restrict__ bnsq) {
    int f = threadIdx.x;
    float s = 0.f, q = 0.f;
    for (int n = blockIdx.x; n < N; n += gridDim.x) {
        float v = xc[(size_t)n * DCAT + off + f];
        s += v;
        q += v * v;
    }
    atomicAdd(&bnsum[f], s);
    atomicAdd(&bnsq[f], q);
}

__global__ __launch_bounds__(128) void bn_affine_kernel(const float* __restrict__ bnsum,
                                                        const float* __restrict__ bnsq,
                                                        const float* __restrict__ gamma,
                                                        const float* __restrict__ beta,
                                                        float* scA, float* shA, int seg_off, float invN) {
    int f = threadIdx.x;
    float mu = bnsum[f] * invN;
    float var = bnsq[f] * invN - mu * mu;
    float rs = rsqrtf(var + 1e-5f);
    float s = gamma[f] * rs;
    scA[seg_off + f] = s;
    shA[seg_off + f] = fmaf(-mu, s, beta[f]);
}

// ---------------- log_softmax (thread per node; reads out_acc ld=64) ---------
__global__ __launch_bounds__(256) void logsoftmax_kernel(const float* __restrict__ oacc,
                                                         float* __restrict__ out, int N) {
    for (int n = blockIdx.x * blockDim.x + threadIdx.x; n < N; n += gridDim.x * blockDim.x) {
        const float* row = oacc + (size_t)n * OOUT;
        float m = -1e30f;
#pragma unroll
        for (int j = 0; j < NCLS; ++j) m = fmaxf(m, row[j]);
        float s = 0.f;
#pragma unroll
        for (int j = 0; j < NCLS; ++j) s += __expf(row[j] - m);
        float lse = m + __logf(s);
        float* orow = out + (size_t)n * NCLS;
#pragma unroll
        for (int j = 0; j < NCLS; ++j) orow[j] = row[j] - lse;
    }
}

// ---------------- launch ----------------

extern "C" void kernel_launch(void* const* d_in, const int* in_sizes, int n_in,
                              void* d_out, int out_size, void* d_ws, size_t ws_size,
                              hipStream_t stream) {
    const float* x            = (const float*)d_in[0];
    const int*   eidx         = (const int*)d_in[1];
    const float* conv_base_w  = (const float*)d_in[3];
    const float* conv_spline_w= (const float*)d_in[4];
    const float* conv_scaler  = (const float*)d_in[5];
    const float* conv_bias    = (const float*)d_in[6];
    const float* bn_gamma     = (const float*)d_in[7];
    const float* bn_beta      = (const float*)d_in[8];
    const float* out_base_w   = (const float*)d_in[10];
    const float* out_spline_w = (const float*)d_in[11];
    const float* out_scaler   = (const float*)d_in[12];
    float* out = (float*)d_out;

    int N = in_sizes[0] / F_IN;
    int E = in_sizes[1] / 2;
    const int* esrc = eidx;
    const int* edst = eidx + E;

    int blocks = (N + 127) / 128;
    int npad = blocks * 128;
    int nsb = (N + 255) / 256;

    char* p = (char*)d_ws;
    auto carve = [&](size_t bytes) {
        char* r = p;
        p += (bytes + 255) & ~(size_t)255;
        return r;
    };
    float* xc   = (float*)carve((size_t)N * DCAT * 4);
    float* htmp = (float*)carve((size_t)npad * HID * 4);
    float* oacc = (float*)carve((size_t)npad * OOUT * 4);
    unsigned short* silbuf = (unsigned short*)carve((size_t)npad * 128 * 2);
    float* dinv = (float*)carve((size_t)N * 4);
    float* bn   = (float*)carve((size_t)NLAYER * 2 * HID * 4);
    float* scA  = (float*)carve((size_t)DCAT * 4);
    float* shA  = (float*)carve((size_t)DCAT * 4);
    unsigned short* wpkc = (unsigned short*)carve((size_t)NLAYER * 9 * 128 * 128 * 2);
    unsigned short* wpko = (unsigned short*)carve((size_t)4 * 9 * 64 * 128 * 2);
    int* deg    = (int*)carve((size_t)N * 4);
    int* offs   = (int*)carve((size_t)(N + 1) * 4);
    int* cursor = (int*)carve((size_t)(N + 1) * 4);
    int* bsum   = (int*)carve((size_t)nsb * 4);
    int* bbase  = (int*)carve((size_t)nsb * 4);
    int* csr    = (int*)carve((size_t)(E + N) * 4);

    hipMemsetAsync(bn, 0, NLAYER * 2 * HID * 4, stream);

    // graph preprocessing
    deg_init_kernel<<<512, 256, 0, stream>>>(deg, N);
    deg_count_kernel<<<1024, 256, 0, stream>>>(edst, E, deg);
    dinv_kernel<<<512, 256, 0, stream>>>(deg, dinv, N);
    scan_reduce_kernel<<<nsb, 256, 0, stream>>>(deg, bsum, N);
    scan_top_kernel<<<1, 256, 0, stream>>>(bsum, bbase, nsb);
    scan_write_kernel<<<nsb, 256, 0, stream>>>(deg, bbase, offs, cursor, N);
    fill_kernel<<<1024, 256, 0, stream>>>(esrc, edst, E, N, cursor, csr);

    // weight packing + x copy + affine init
    pack_conv_mfma<<<1024, 256, 0, stream>>>(conv_base_w, conv_spline_w, conv_scaler, wpkc);
    pack_out_mfma<<<1024, 256, 0, stream>>>(out_base_w, out_spline_w, out_scaler, wpko);
    copyx_kernel<<<2048, 256, 0, stream>>>(x, xc, N);
    affine_init_kernel<<<1, 512, 0, stream>>>(scA, shA);

    float invN = 1.f / (float)N;
    for (int l = 0; l < NLAYER; ++l) {
        int in_off = l * HID;
        int out_off = (l + 1) * HID;
        const unsigned short* wl = wpkc + (size_t)l * 9 * 128 * 128;
        const unsigned short* wo = wpko + (size_t)l * 9 * 64 * 128;
        silu_prep_kernel<<<1024, 256, 0, stream>>>(xc, in_off, scA, shA, silbuf, N);
        if (l == 0)
            kan_fused_kernel<true, true><<<blocks, 256, 0, stream>>>(
                xc, in_off, scA, shA, wl, wo, silbuf, htmp, oacc, N);
        else
            kan_fused_kernel<true, false><<<blocks, 256, 0, stream>>>(
                xc, in_off, scA, shA, wl, wo, silbuf, htmp, oacc, N);
        agg_kernel<<<(N + 3) / 4, 256, 0, stream>>>(htmp, dinv, offs, csr, conv_bias + l * HID, xc, out_off, N);
        float* bnsum = bn + l * 2 * HID;
        float* bnsq  = bnsum + HID;
        bn_stats_kernel<<<256, 128, 0, stream>>>(xc, out_off, N, bnsum, bnsq);
        bn_affine_kernel<<<1, 128, 0, stream>>>(bnsum, bnsq, bn_gamma + l * HID, bn_beta + l * HID,
                                                scA, shA, out_off, invN);
    }

    // segment 3 (final BN output) -> out partial
    silu_prep_kernel<<<1024, 256, 0, stream>>>(xc, 384, scA, shA, silbuf, N);
    kan_fused_kernel<false, false><<<blocks, 256, 0, stream>>>(
        xc, 384, scA, shA, nullptr, wpko + (size_t)3 * 9 * 64 * 128, silbuf, nullptr, oacc, N);

    logsoftmax_kernel<<<(N + 255) / 256, 256, 0, stream>>>(oacc, out, N);
}

// Round 7
// 622.866 us; speedup vs baseline: 1.4385x; 1.0554x over previous
//
#include <hip/hip_runtime.h>
#include <hip/hip_bf16.h>
#include <math.h>

#define F_IN   128
#define HID    128
#define NLAYER 3
#define NCLS   40
#define DCAT   512   // F_IN + NLAYER*HID
#define OOUT   64    // padded out-layer cols

typedef short s16x8 __attribute__((ext_vector_type(8)));
typedef unsigned short u16x8 __attribute__((ext_vector_type(8)));
typedef unsigned short u16x4 __attribute__((ext_vector_type(4)));
typedef float f32x4 __attribute__((ext_vector_type(4)));

// ---------------- device helpers ----------------

static __device__ __forceinline__ float silu_f(float x) {
    return x / (1.f + __expf(-x));
}

static __device__ __forceinline__ unsigned short f2bf_rn(float f) {
    union { __hip_bfloat16 h; unsigned short u; } cv;
    cv.h = __float2bfloat16(f);
    return cv.u;
}

static __device__ __forceinline__ void gload_lds16(const void* g, void* l) {
    __builtin_amdgcn_global_load_lds(
        (const __attribute__((address_space(1))) void*)g,
        (__attribute__((address_space(3))) void*)l, 16, 0, 0);
}

// ---------------- graph preprocessing ----------------

__global__ __launch_bounds__(256) void deg_init_kernel(int* deg, int N) {
    for (int i = blockIdx.x * blockDim.x + threadIdx.x; i < N; i += gridDim.x * blockDim.x)
        deg[i] = 1;  // self-loop
}

__global__ __launch_bounds__(256) void deg_count_kernel(const int* __restrict__ dst, int E, int* deg) {
    for (int i = blockIdx.x * blockDim.x + threadIdx.x; i < E; i += gridDim.x * blockDim.x)
        atomicAdd(&deg[dst[i]], 1);
}

__global__ __launch_bounds__(256) void dinv_kernel(const int* __restrict__ deg, float* dinv, int N) {
    for (int i = blockIdx.x * blockDim.x + threadIdx.x; i < N; i += gridDim.x * blockDim.x)
        dinv[i] = rsqrtf((float)deg[i]);
}

// hierarchical scan: 1 elem/thread, 256/block
__global__ __launch_bounds__(256) void scan_reduce_kernel(const int* __restrict__ deg, int* __restrict__ bsum, int N) {
    __shared__ int sh[256];
    int t = threadIdx.x;
    int e = blockIdx.x * 256 + t;
    sh[t] = (e < N) ? deg[e] : 0;
    __syncthreads();
#pragma unroll
    for (int off = 128; off > 0; off >>= 1) {
        if (t < off) sh[t] += sh[t + off];
        __syncthreads();
    }
    if (t == 0) bsum[blockIdx.x] = sh[0];
}

__global__ __launch_bounds__(256) void scan_top_kernel(const int* __restrict__ bsum, int* __restrict__ bbase, int nsb) {
    __shared__ int sh[256];
    int t = threadIdx.x;
    int chunk = (nsb + 255) >> 8;
    int begin = t * chunk;
    int end = begin + chunk; if (end > nsb) end = nsb;
    int s = 0;
    for (int i = begin; i < end; ++i) s += bsum[i];
    sh[t] = s;
    __syncthreads();
#pragma unroll
    for (int off = 1; off < 256; off <<= 1) {
        int v = 0;
        if (t >= off) v = sh[t - off];
        __syncthreads();
        if (t >= off) sh[t] += v;
        __syncthreads();
    }
    int run = (t == 0) ? 0 : sh[t - 1];
    for (int i = begin; i < end; ++i) {
        bbase[i] = run;
        run += bsum[i];
    }
}

__global__ __launch_bounds__(256) void scan_write_kernel(const int* __restrict__ deg,
                                                         const int* __restrict__ bbase,
                                                         int* __restrict__ offs, int* __restrict__ cursor, int N) {
    __shared__ int sh[256];
    int t = threadIdx.x;
    int e = blockIdx.x * 256 + t;
    int d = (e < N) ? deg[e] : 0;
    sh[t] = d;
    __syncthreads();
#pragma unroll
    for (int off = 1; off < 256; off <<= 1) {
        int v = 0;
        if (t >= off) v = sh[t - off];
        __syncthreads();
        if (t >= off) sh[t] += v;
        __syncthreads();
    }
    int incl = sh[t] + bbase[blockIdx.x];
    int excl = incl - d;
    if (e < N) {
        offs[e] = excl;
        cursor[e] = excl;
        if (e == N - 1) offs[N] = incl;
    }
}

__global__ __launch_bounds__(256) void fill_kernel(const int* __restrict__ src, const int* __restrict__ dst,
                                                   int E, int N, int* cursor, int* __restrict__ csr) {
    int total = E + N;
    for (int i = blockIdx.x * blockDim.x + threadIdx.x; i < total; i += gridDim.x * blockDim.x) {
        if (i < E) {
            int d = dst[i];
            int p = atomicAdd(&cursor[d], 1);
            csr[p] = src[i];
        } else {
            int n = i - E;
            int p = atomicAdd(&cursor[n], 1);
            csr[p] = n;
        }
    }
}

// ---------------- weight packing (bf16, pre-swizzled, chunk order sp0..sp7,silu) ---
// Per chunk [o][kd] with kd = k ^ ((o&7)<<3).
// conv: [l][cc(9)][o(128)][kd(128)]
__global__ __launch_bounds__(256) void pack_conv_mfma(const float* __restrict__ bw,
                                                      const float* __restrict__ sw,
                                                      const float* __restrict__ sc,
                                                      unsigned short* __restrict__ wpk) {
    int total = NLAYER * 9 * 128 * 128;
    for (int idx = blockIdx.x * blockDim.x + threadIdx.x; idx < total; idx += gridDim.x * blockDim.x) {
        int kd = idx & 127;
        int o  = (idx >> 7) & 127;
        int cc = (idx >> 14) % 9;
        int l  = idx / (9 << 14);
        int k = kd ^ ((o & 7) << 3);   // logical k
        float v;
        if (cc == 8) {                 // silu chunk
            v = bw[(l * 128 + o) * 128 + k];
        } else {                       // spline chunk: 16 feats x 8 bases
            int f = cc * 16 + (k >> 3);
            int j = k & 7;
            int base = (l * 128 + o) * 128 + f;
            v = sw[base * 8 + j] * sc[base];
        }
        wpk[idx] = f2bf_rn(v);
    }
}

// out: [g(4)][cc(9)][o(64)][kd(128)], cols >= NCLS zeroed
__global__ __launch_bounds__(256) void pack_out_mfma(const float* __restrict__ bw,
                                                     const float* __restrict__ sw,
                                                     const float* __restrict__ sc,
                                                     unsigned short* __restrict__ wpk) {
    int total = 4 * 9 * 64 * 128;
    for (int idx = blockIdx.x * blockDim.x + threadIdx.x; idx < total; idx += gridDim.x * blockDim.x) {
        int kd = idx & 127;
        int o  = (idx >> 7) & 63;
        int cc = (idx >> 13) % 9;
        int g  = idx / (9 << 13);
        int k = kd ^ ((o & 7) << 3);
        float v = 0.f;
        if (o < NCLS) {
            if (cc == 8) {
                int f = g * 128 + k;
                v = bw[o * DCAT + f];
            } else {
                int f = g * 128 + cc * 16 + (k >> 3);
                int j = k & 7;
                int base = o * DCAT + f;
                v = sw[base * 8 + j] * sc[base];
            }
        }
        wpk[idx] = f2bf_rn(v);
    }
}

// ---------------- misc data movement ----------------

__global__ __launch_bounds__(256) void copyx_kernel(const float* __restrict__ x, float* __restrict__ xc, int N) {
    int total = N * F_IN;
    for (int idx = blockIdx.x * blockDim.x + threadIdx.x; idx < total; idx += gridDim.x * blockDim.x) {
        int n = idx >> 7, f = idx & 127;
        xc[(size_t)n * DCAT + f] = x[idx];
    }
}

__global__ __launch_bounds__(512) void affine_init_kernel(float* scA, float* shA) {
    int i = threadIdx.x;
    scA[i] = 1.f; shA[i] = 0.f;
}

// ---------------- fused KAN GEMM + out-layer partial (bf16 MFMA 16x16x32) ----
// Block: 256 threads (4 waves 2x2), tile 128 nodes.
// Chunks 0..7: spline (16 feats x 8 bases, K=128); silu(y) for those feats is
// emitted to silbuf (global, swizzled bf16) as a side product. Chunk 8: silu,
// staged back from silbuf via global_load_lds (same block -> same L2, visible
// after the barrier's vmcnt drain).
// Conv branch (CONV): 128 cols -> htmp (bf16). Out branch: 64 cols -> out_acc.
// LDS rows 256B, XOR swizzle byte ^= ((row&7)<<4); W pre-swizzled in global.
template<bool CONV, bool INIT>
__global__ __launch_bounds__(256, 2) void kan_fused_kernel(
    const float* __restrict__ xc, int in_off,
    const float* __restrict__ scA, const float* __restrict__ shA,
    const unsigned short* __restrict__ wconv,
    const unsigned short* __restrict__ wout,
    unsigned short* __restrict__ silbuf,
    unsigned short* __restrict__ htmp,
    float* __restrict__ out_acc, int N) {

    constexpr int LDS_WC = CONV ? 32768 : 0;
    __shared__ __align__(16) char lds[32768 + LDS_WC + 16384];
    char* lds_phi = lds;
    char* lds_wc  = lds + 32768;
    char* lds_wo  = lds + 32768 + LDS_WC;

    const int tid = threadIdx.x;
    const int lane = tid & 63;
    const int wave = tid >> 6;
    const int wr = wave >> 1, wc = wave & 1;
    const int l15 = lane & 15, lg = lane >> 4;
    const int nblk = blockIdx.x * 128;

    const float g0 = -1.f - 3.f * 0.4f;
    const float invh = 1.f / 0.4f;

    // spline staging decomposition: (fg = tid&3 : 4 features), nodes {n0, n0+64}
    const int fg = tid & 3;
    const int n0 = tid >> 2;

    f32x4 accc[4][4];   // conv 128 cols
    f32x4 acco[4][2];   // out 64 cols
    if (CONV) {
#pragma unroll
        for (int r = 0; r < 4; ++r)
#pragma unroll
            for (int c = 0; c < 4; ++c) accc[r][c] = (f32x4)0.f;
    }
#pragma unroll
    for (int r = 0; r < 4; ++r)
#pragma unroll
        for (int c = 0; c < 2; ++c) acco[r][c] = (f32x4)0.f;

    float4 xq[2], scq, shq;
    auto ldx = [&](int cc) {
        int f0 = in_off + cc * 16 + fg * 4;
        scq = *(const float4*)(scA + f0);
        shq = *(const float4*)(shA + f0);
        int gn0 = nblk + n0, gn1 = gn0 + 64;
        xq[0] = (gn0 < N) ? *(const float4*)(xc + (size_t)gn0 * DCAT + f0) : (float4){0.f,0.f,0.f,0.f};
        xq[1] = (gn1 < N) ? *(const float4*)(xc + (size_t)gn1 * DCAT + f0) : (float4){0.f,0.f,0.f,0.f};
    };

    u16x8 pcur[2][4];
    auto phi_compute = [&](int ccc) {
#pragma unroll
        for (int g2 = 0; g2 < 2; ++g2) {
            float xi[4] = {xq[g2].x, xq[g2].y, xq[g2].z, xq[g2].w};
            float scr[4] = {scq.x, scq.y, scq.z, scq.w};
            float shr[4] = {shq.x, shq.y, shq.z, shq.w};
            u16x4 sv;
#pragma unroll
            for (int fl = 0; fl < 4; ++fl) {
                float y = fmaf(xi[fl], scr[fl], shr[fl]);
                // silu side product (for chunk 8)
                sv[fl] = f2bf_rn(silu_f(y));
                float t = (y - g0) * invh;
                float cf = floorf(t);
                int c = (int)cf;
                float u = t - cf;
                float um = 1.f - u;
                float u2 = u * u;
                float um2 = um * um;
                float w0 = um2 * um * (1.f / 6.f);
                float w3 = u2 * u * (1.f / 6.f);
                float w1 = fmaf(fmaf(0.5f, u, -1.f), u2, 2.f / 3.f);
                float w2 = fmaf(fmaf(-0.5f, u, 0.5f), u2, fmaf(0.5f, u, 1.f / 6.f));
                bool e[11];
#pragma unroll
                for (int v = 0; v < 11; ++v) e[v] = (c == v);
#pragma unroll
                for (int s = 0; s < 8; ++s) {
                    float val = 0.f;
                    val = e[s] ? w3 : val;
                    val = e[s + 1] ? w2 : val;
                    val = e[s + 2] ? w1 : val;
                    val = e[s + 3] ? w0 : val;
                    pcur[g2][fl][s] = f2bf_rn(val);
                }
            }
            int gn = nblk + n0 + g2 * 64;
            if (gn < N) {
                int fdst = (ccc * 16 + fg * 4) ^ ((n0 & 7) << 3);
                *(u16x4*)(silbuf + (size_t)gn * 128 + fdst) = sv;
            }
        }
    };

    auto stage_w = [&](int cc) {
        if (CONV) {
            const unsigned short* wcsrc = wconv + (size_t)cc * 128 * 128;
#pragma unroll
            for (int i = 0; i < 8; ++i) {
                int e = tid + i * 256;
                gload_lds16(wcsrc + e * 8, lds_wc + e * 16);
            }
        }
        const unsigned short* wosrc = wout + (size_t)cc * 64 * 128;
#pragma unroll
        for (int i = 0; i < 4; ++i) {
            int e = tid + i * 256;
            gload_lds16(wosrc + e * 8, lds_wo + e * 16);
        }
    };

    auto mfma_phase = [&]() {
#pragma unroll
        for (int kk = 0; kk < 4; ++kk) {
            const int kb = kk * 64 + lg * 16;
            s16x8 af[4];
#pragma unroll
            for (int r = 0; r < 4; ++r) {
                int n = wr * 64 + r * 16 + l15;
                af[r] = *(const s16x8*)(lds_phi + n * 256 + (kb ^ ((n & 7) << 4)));
            }
            if (CONV) {
#pragma unroll
                for (int c = 0; c < 4; ++c) {
                    int o = wc * 64 + c * 16 + l15;
                    s16x8 b = *(const s16x8*)(lds_wc + o * 256 + (kb ^ ((o & 7) << 4)));
#pragma unroll
                    for (int r = 0; r < 4; ++r)
                        accc[r][c] = __builtin_amdgcn_mfma_f32_16x16x32_bf16(af[r], b, accc[r][c], 0, 0, 0);
                }
            }
#pragma unroll
            for (int c = 0; c < 2; ++c) {
                int o = wc * 32 + c * 16 + l15;
                s16x8 b = *(const s16x8*)(lds_wo + o * 256 + (kb ^ ((o & 7) << 4)));
#pragma unroll
                for (int r = 0; r < 4; ++r)
                    acco[r][c] = __builtin_amdgcn_mfma_f32_16x16x32_bf16(af[r], b, acco[r][c], 0, 0, 0);
            }
        }
    };

    // prologue: chunk 0 phi
    ldx(0);
    phi_compute(0);

    for (int cc = 0; cc < 8; ++cc) {
        __syncthreads();                   // prev MFMA done with LDS
        stage_w(cc);                       // async W -> LDS
        // write phi regs -> LDS
#pragma unroll
        for (int g2 = 0; g2 < 2; ++g2) {
            int n = n0 + g2 * 64;
            int swz = (n & 7) << 4;
#pragma unroll
            for (int i = 0; i < 4; ++i) {
                int byte = n * 256 + ((fg * 64 + i * 16) ^ swz);
                *(u16x8*)(lds_phi + byte) = pcur[g2][i];
            }
        }
        __syncthreads();                   // drains vmcnt+lds: W & phi ready
        if (cc < 7) ldx(cc + 1);           // issue next x loads (hidden by MFMA)
        mfma_phase();
        if (cc < 7) phi_compute(cc + 1);   // overlaps MFMA (separate pipes)
    }

    // silu chunk (cc=8): staged back from silbuf, zero VALU
    __syncthreads();                       // also drains this block's silbuf stores
    stage_w(8);
    {
        const unsigned short* ssrc = silbuf + (size_t)nblk * 128;
#pragma unroll
        for (int i = 0; i < 8; ++i) {
            int e = tid + i * 256;
            gload_lds16(ssrc + e * 8, lds_phi + e * 16);
        }
    }
    __syncthreads();
    mfma_phase();

    // epilogue
#pragma unroll
    for (int r = 0; r < 4; ++r) {
        int nb = nblk + wr * 64 + r * 16 + lg * 4;
        if (CONV) {
#pragma unroll
            for (int c = 0; c < 4; ++c) {
                int o = wc * 64 + c * 16 + l15;
#pragma unroll
                for (int q = 0; q < 4; ++q) {
                    int n = nb + q;
                    if (n < N) htmp[(size_t)n * HID + o] = f2bf_rn(accc[r][c][q]);
                }
            }
        }
#pragma unroll
        for (int c = 0; c < 2; ++c) {
            int o = wc * 32 + c * 16 + l15;
#pragma unroll
            for (int q = 0; q < 4; ++q) {
                int n = nb + q;
                if (n < N) {
                    size_t a = (size_t)n * OOUT + o;
                    float v = acco[r][c][q];
                    if (!INIT) v += out_acc[a];
                    out_acc[a] = v;
                }
            }
        }
    }
}

// ---------------- aggregation (one wave per node, bf16 h rows) ---------------
__global__ __launch_bounds__(256) void agg_kernel(const unsigned short* __restrict__ h,
                                                  const float* __restrict__ dinv,
                                                  const int* __restrict__ offs,
                                                  const int* __restrict__ csr,
                                                  const float* __restrict__ bias,
                                                  float* __restrict__ xc, int out_off, int N) {
    int n = blockIdx.x * 4 + (threadIdx.x >> 6);
    if (n >= N) return;
    int lane = threadIdx.x & 63;
    int s = offs[n], e = offs[n + 1];
    float a0 = 0.f, a1 = 0.f;
    for (int i = s; i < e; ++i) {
        int v = csr[i];
        float dv = dinv[v];
        unsigned u = *(const unsigned*)(h + (size_t)v * HID + lane * 2);
        float h0 = __uint_as_float(u << 16);
        float h1 = __uint_as_float(u & 0xffff0000u);
        a0 = fmaf(h0, dv, a0);
        a1 = fmaf(h1, dv, a1);
    }
    float dn = dinv[n];
    float2 bv = *(const float2*)(bias + lane * 2);
    float2 res = {a0 * dn + bv.x, a1 * dn + bv.y};
    *(float2*)(xc + (size_t)n * DCAT + out_off + lane * 2) = res;
}

// ---------------- batchnorm stats + deferred affine ----------------
__global__ __launch_bounds__(128) void bn_stats_kernel(const float* __restrict__ xc, int off, int N,
                                                       float* __restrict__ bnsum, float* __restrict__ bnsq) {
    int f = threadIdx.x;
    float s = 0.f, q = 0.f;
    for (int n = blockIdx.x; n < N; n += gridDim.x) {
        float v = xc[(size_t)n * DCAT + off + f];
        s += v;
        q += v * v;
    }
    atomicAdd(&bnsum[f], s);
    atomicAdd(&bnsq[f], q);
}

__global__ __launch_bounds__(128) void bn_affine_kernel(const float* __restrict__ bnsum,
                                                        const float* __restrict__ bnsq,
                                                        const float* __restrict__ gamma,
                                                        const float* __restrict__ beta,
                                                        float* scA, float* shA, int seg_off, float invN) {
    int f = threadIdx.x;
    float mu = bnsum[f] * invN;
    float var = bnsq[f] * invN - mu * mu;
    float rs = rsqrtf(var + 1e-5f);
    float s = gamma[f] * rs;
    scA[seg_off + f] = s;
    shA[seg_off + f] = fmaf(-mu, s, beta[f]);
}

// ---------------- log_softmax (thread per node; reads out_acc ld=64) ---------
__global__ __launch_bounds__(256) void logsoftmax_kernel(const float* __restrict__ oacc,
                                                         float* __restrict__ out, int N) {
    for (int n = blockIdx.x * blockDim.x + threadIdx.x; n < N; n += gridDim.x * blockDim.x) {
        const float* row = oacc + (size_t)n * OOUT;
        float m = -1e30f;
#pragma unroll
        for (int j = 0; j < NCLS; ++j) m = fmaxf(m, row[j]);
        float s = 0.f;
#pragma unroll
        for (int j = 0; j < NCLS; ++j) s += __expf(row[j] - m);
        float lse = m + __logf(s);
        float* orow = out + (size_t)n * NCLS;
#pragma unroll
        for (int j = 0; j < NCLS; ++j) orow[j] = row[j] - lse;
    }
}

// ---------------- launch ----------------

extern "C" void kernel_launch(void* const* d_in, const int* in_sizes, int n_in,
                              void* d_out, int out_size, void* d_ws, size_t ws_size,
                              hipStream_t stream) {
    const float* x            = (const float*)d_in[0];
    const int*   eidx         = (const int*)d_in[1];
    const float* conv_base_w  = (const float*)d_in[3];
    const float* conv_spline_w= (const float*)d_in[4];
    const float* conv_scaler  = (const float*)d_in[5];
    const float* conv_bias    = (const float*)d_in[6];
    const float* bn_gamma     = (const float*)d_in[7];
    const float* bn_beta      = (const float*)d_in[8];
    const float* out_base_w   = (const float*)d_in[10];
    const float* out_spline_w = (const float*)d_in[11];
    const float* out_scaler   = (const float*)d_in[12];
    float* out = (float*)d_out;

    int N = in_sizes[0] / F_IN;
    int E = in_sizes[1] / 2;
    const int* esrc = eidx;
    const int* edst = eidx + E;

    int blocks = (N + 127) / 128;
    int npad = blocks * 128;
    int nsb = (N + 255) / 256;

    char* p = (char*)d_ws;
    auto carve = [&](size_t bytes) {
        char* r = p;
        p += (bytes + 255) & ~(size_t)255;
        return r;
    };
    float* xc   = (float*)carve((size_t)N * DCAT * 4);
    unsigned short* htmp = (unsigned short*)carve((size_t)npad * HID * 2);
    float* oacc = (float*)carve((size_t)npad * OOUT * 4);
    unsigned short* silbuf = (unsigned short*)carve((size_t)npad * 128 * 2);
    float* dinv = (float*)carve((size_t)N * 4);
    float* bn   = (float*)carve((size_t)NLAYER * 2 * HID * 4);
    float* scA  = (float*)carve((size_t)DCAT * 4);
    float* shA  = (float*)carve((size_t)DCAT * 4);
    unsigned short* wpkc = (unsigned short*)carve((size_t)NLAYER * 9 * 128 * 128 * 2);
    unsigned short* wpko = (unsigned short*)carve((size_t)4 * 9 * 64 * 128 * 2);
    int* deg    = (int*)carve((size_t)N * 4);
    int* offs   = (int*)carve((size_t)(N + 1) * 4);
    int* cursor = (int*)carve((size_t)(N + 1) * 4);
    int* bsum   = (int*)carve((size_t)nsb * 4);
    int* bbase  = (int*)carve((size_t)nsb * 4);
    int* csr    = (int*)carve((size_t)(E + N) * 4);

    hipMemsetAsync(bn, 0, NLAYER * 2 * HID * 4, stream);

    // graph preprocessing
    deg_init_kernel<<<512, 256, 0, stream>>>(deg, N);
    deg_count_kernel<<<1024, 256, 0, stream>>>(edst, E, deg);
    dinv_kernel<<<512, 256, 0, stream>>>(deg, dinv, N);
    scan_reduce_kernel<<<nsb, 256, 0, stream>>>(deg, bsum, N);
    scan_top_kernel<<<1, 256, 0, stream>>>(bsum, bbase, nsb);
    scan_write_kernel<<<nsb, 256, 0, stream>>>(deg, bbase, offs, cursor, N);
    fill_kernel<<<1024, 256, 0, stream>>>(esrc, edst, E, N, cursor, csr);

    // weight packing + x copy + affine init
    pack_conv_mfma<<<1024, 256, 0, stream>>>(conv_base_w, conv_spline_w, conv_scaler, wpkc);
    pack_out_mfma<<<1024, 256, 0, stream>>>(out_base_w, out_spline_w, out_scaler, wpko);
    copyx_kernel<<<2048, 256, 0, stream>>>(x, xc, N);
    affine_init_kernel<<<1, 512, 0, stream>>>(scA, shA);

    float invN = 1.f / (float)N;
    for (int l = 0; l < NLAYER; ++l) {
        int in_off = l * HID;
        int out_off = (l + 1) * HID;
        const unsigned short* wl = wpkc + (size_t)l * 9 * 128 * 128;
        const unsigned short* wo = wpko + (size_t)l * 9 * 64 * 128;
        if (l == 0)
            kan_fused_kernel<true, true><<<blocks, 256, 0, stream>>>(
                xc, in_off, scA, shA, wl, wo, silbuf, htmp, oacc, N);
        else
            kan_fused_kernel<true, false><<<blocks, 256, 0, stream>>>(
                xc, in_off, scA, shA, wl, wo, silbuf, htmp, oacc, N);
        agg_kernel<<<(N + 3) / 4, 256, 0, stream>>>(htmp, dinv, offs, csr, conv_bias + l * HID, xc, out_off, N);
        float* bnsum = bn + l * 2 * HID;
        float* bnsq  = bnsum + HID;
        bn_stats_kernel<<<256, 128, 0, stream>>>(xc, out_off, N, bnsum, bnsq);
        bn_affine_kernel<<<1, 128, 0, stream>>>(bnsum, bnsq, bn_gamma + l * HID, bn_beta + l * HID,
                                                scA, shA, out_off, invN);
    }

    // segment 3 (final BN output) -> out partial
    kan_fused_kernel<false, false><<<blocks, 256, 0, stream>>>(
        xc, 384, scA, shA, nullptr, wpko + (size_t)3 * 9 * 64 * 128, silbuf, nullptr, oacc, N);

    logsoftmax_kernel<<<(N + 255) / 256, 256, 0, stream>>>(oacc, out, N);
}

// Round 8
// 561.504 us; speedup vs baseline: 1.5957x; 1.1093x over previous
//
#include <hip/hip_runtime.h>
#include <hip/hip_bf16.h>
#include <math.h>

#define F_IN   128
#define HID    128
#define NLAYER 3
#define NCLS   40
#define DCAT   512   // F_IN + NLAYER*HID
#define OOUT   64    // padded out-layer cols

typedef short s16x8 __attribute__((ext_vector_type(8)));
typedef unsigned short u16x8 __attribute__((ext_vector_type(8)));
typedef unsigned short u16x4 __attribute__((ext_vector_type(4)));
typedef float f32x4 __attribute__((ext_vector_type(4)));

// ---------------- device helpers ----------------

static __device__ __forceinline__ float silu_f(float x) {
    return x / (1.f + __expf(-x));
}

static __device__ __forceinline__ unsigned short f2bf_rn(float f) {
    union { __hip_bfloat16 h; unsigned short u; } cv;
    cv.h = __float2bfloat16(f);
    return cv.u;
}

static __device__ __forceinline__ void gload_lds16(const void* g, void* l) {
    __builtin_amdgcn_global_load_lds(
        (const __attribute__((address_space(1))) void*)g,
        (__attribute__((address_space(3))) void*)l, 16, 0, 0);
}

// ---------------- graph preprocessing ----------------

__global__ __launch_bounds__(256) void deg_init_kernel(int* deg, int N) {
    for (int i = blockIdx.x * blockDim.x + threadIdx.x; i < N; i += gridDim.x * blockDim.x)
        deg[i] = 1;  // self-loop
}

__global__ __launch_bounds__(256) void deg_count_kernel(const int* __restrict__ dst, int E, int* deg) {
    for (int i = blockIdx.x * blockDim.x + threadIdx.x; i < E; i += gridDim.x * blockDim.x)
        atomicAdd(&deg[dst[i]], 1);
}

__global__ __launch_bounds__(256) void dinv_kernel(const int* __restrict__ deg, float* dinv, int N) {
    for (int i = blockIdx.x * blockDim.x + threadIdx.x; i < N; i += gridDim.x * blockDim.x)
        dinv[i] = rsqrtf((float)deg[i]);
}

// hierarchical scan: 1 elem/thread, 256/block
__global__ __launch_bounds__(256) void scan_reduce_kernel(const int* __restrict__ deg, int* __restrict__ bsum, int N) {
    __shared__ int sh[256];
    int t = threadIdx.x;
    int e = blockIdx.x * 256 + t;
    sh[t] = (e < N) ? deg[e] : 0;
    __syncthreads();
#pragma unroll
    for (int off = 128; off > 0; off >>= 1) {
        if (t < off) sh[t] += sh[t + off];
        __syncthreads();
    }
    if (t == 0) bsum[blockIdx.x] = sh[0];
}

__global__ __launch_bounds__(256) void scan_top_kernel(const int* __restrict__ bsum, int* __restrict__ bbase, int nsb) {
    __shared__ int sh[256];
    int t = threadIdx.x;
    int chunk = (nsb + 255) >> 8;
    int begin = t * chunk;
    int end = begin + chunk; if (end > nsb) end = nsb;
    int s = 0;
    for (int i = begin; i < end; ++i) s += bsum[i];
    sh[t] = s;
    __syncthreads();
#pragma unroll
    for (int off = 1; off < 256; off <<= 1) {
        int v = 0;
        if (t >= off) v = sh[t - off];
        __syncthreads();
        if (t >= off) sh[t] += v;
        __syncthreads();
    }
    int run = (t == 0) ? 0 : sh[t - 1];
    for (int i = begin; i < end; ++i) {
        bbase[i] = run;
        run += bsum[i];
    }
}

__global__ __launch_bounds__(256) void scan_write_kernel(const int* __restrict__ deg,
                                                         const int* __restrict__ bbase,
                                                         int* __restrict__ offs, int* __restrict__ cursor, int N) {
    __shared__ int sh[256];
    int t = threadIdx.x;
    int e = blockIdx.x * 256 + t;
    int d = (e < N) ? deg[e] : 0;
    sh[t] = d;
    __syncthreads();
#pragma unroll
    for (int off = 1; off < 256; off <<= 1) {
        int v = 0;
        if (t >= off) v = sh[t - off];
        __syncthreads();
        if (t >= off) sh[t] += v;
        __syncthreads();
    }
    int incl = sh[t] + bbase[blockIdx.x];
    int excl = incl - d;
    if (e < N) {
        offs[e] = excl;
        cursor[e] = excl;
        if (e == N - 1) offs[N] = incl;
    }
}

__global__ __launch_bounds__(256) void fill_kernel(const int* __restrict__ src, const int* __restrict__ dst,
                                                   int E, int N, int* cursor, int* __restrict__ csr) {
    int total = E + N;
    for (int i = blockIdx.x * blockDim.x + threadIdx.x; i < total; i += gridDim.x * blockDim.x) {
        if (i < E) {
            int d = dst[i];
            int p = atomicAdd(&cursor[d], 1);
            csr[p] = src[i];
        } else {
            int n = i - E;
            int p = atomicAdd(&cursor[n], 1);
            csr[p] = n;
        }
    }
}

// ---------------- weight packing (bf16, pre-swizzled, chunk order sp0..sp7,silu) ---
// Per chunk [o][kd] with kd = k ^ ((o&7)<<3).
// conv: [l][cc(9)][o(128)][kd(128)]
__global__ __launch_bounds__(256) void pack_conv_mfma(const float* __restrict__ bw,
                                                      const float* __restrict__ sw,
                                                      const float* __restrict__ sc,
                                                      unsigned short* __restrict__ wpk) {
    int total = NLAYER * 9 * 128 * 128;
    for (int idx = blockIdx.x * blockDim.x + threadIdx.x; idx < total; idx += gridDim.x * blockDim.x) {
        int kd = idx & 127;
        int o  = (idx >> 7) & 127;
        int cc = (idx >> 14) % 9;
        int l  = idx / (9 << 14);
        int k = kd ^ ((o & 7) << 3);   // logical k
        float v;
        if (cc == 8) {                 // silu chunk
            v = bw[(l * 128 + o) * 128 + k];
        } else {                       // spline chunk: 16 feats x 8 bases
            int f = cc * 16 + (k >> 3);
            int j = k & 7;
            int base = (l * 128 + o) * 128 + f;
            v = sw[base * 8 + j] * sc[base];
        }
        wpk[idx] = f2bf_rn(v);
    }
}

// out: [g(4)][cc(9)][o(64)][kd(128)], cols >= NCLS zeroed
__global__ __launch_bounds__(256) void pack_out_mfma(const float* __restrict__ bw,
                                                     const float* __restrict__ sw,
                                                     const float* __restrict__ sc,
                                                     unsigned short* __restrict__ wpk) {
    int total = 4 * 9 * 64 * 128;
    for (int idx = blockIdx.x * blockDim.x + threadIdx.x; idx < total; idx += gridDim.x * blockDim.x) {
        int kd = idx & 127;
        int o  = (idx >> 7) & 63;
        int cc = (idx >> 13) % 9;
        int g  = idx / (9 << 13);
        int k = kd ^ ((o & 7) << 3);
        float v = 0.f;
        if (o < NCLS) {
            if (cc == 8) {
                int f = g * 128 + k;
                v = bw[o * DCAT + f];
            } else {
                int f = g * 128 + cc * 16 + (k >> 3);
                int j = k & 7;
                int base = o * DCAT + f;
                v = sw[base * 8 + j] * sc[base];
            }
        }
        wpk[idx] = f2bf_rn(v);
    }
}

// ---------------- misc data movement ----------------

__global__ __launch_bounds__(256) void copyx_kernel(const float* __restrict__ x, float* __restrict__ xc, int N) {
    int total = N * F_IN;
    for (int idx = blockIdx.x * blockDim.x + threadIdx.x; idx < total; idx += gridDim.x * blockDim.x) {
        int n = idx >> 7, f = idx & 127;
        xc[(size_t)n * DCAT + f] = x[idx];
    }
}

__global__ __launch_bounds__(512) void affine_init_kernel(float* scA, float* shA) {
    int i = threadIdx.x;
    scA[i] = 1.f; shA[i] = 0.f;
}

// ---------------- fused KAN GEMM + out-layer partial (bf16 MFMA 16x16x32) ----
// Block: 256 threads (4 waves 2x2), tile 128 nodes.
// Chunks 0..7: spline (16 feats x 8 bases, K=128); silu(y) emitted to silbuf.
// Chunk 8: silu, staged back from silbuf via global_load_lds.
// Conv branch (CONV): 128 cols -> htmp = bf16(h * dinv[n]). Out: 64 cols -> out_acc.
// LDS rows 256B, XOR swizzle byte ^= ((row&7)<<4); W pre-swizzled in global.
template<bool CONV, bool INIT>
__global__ __launch_bounds__(256, 2) void kan_fused_kernel(
    const float* __restrict__ xc, int in_off,
    const float* __restrict__ scA, const float* __restrict__ shA,
    const unsigned short* __restrict__ wconv,
    const unsigned short* __restrict__ wout,
    unsigned short* __restrict__ silbuf,
    unsigned short* __restrict__ htmp,
    const float* __restrict__ dinv,
    float* __restrict__ out_acc, int N) {

    constexpr int LDS_WC = CONV ? 32768 : 0;
    __shared__ __align__(16) char lds[32768 + LDS_WC + 16384];
    char* lds_phi = lds;
    char* lds_wc  = lds + 32768;
    char* lds_wo  = lds + 32768 + LDS_WC;

    const int tid = threadIdx.x;
    const int lane = tid & 63;
    const int wave = tid >> 6;
    const int wr = wave >> 1, wc = wave & 1;
    const int l15 = lane & 15, lg = lane >> 4;
    const int nblk = blockIdx.x * 128;

    const float g0 = -1.f - 3.f * 0.4f;
    const float invh = 1.f / 0.4f;

    // spline staging decomposition: (fg = tid&3 : 4 features), nodes {n0, n0+64}
    const int fg = tid & 3;
    const int n0 = tid >> 2;

    f32x4 accc[4][4];   // conv 128 cols
    f32x4 acco[4][2];   // out 64 cols
    if (CONV) {
#pragma unroll
        for (int r = 0; r < 4; ++r)
#pragma unroll
            for (int c = 0; c < 4; ++c) accc[r][c] = (f32x4)0.f;
    }
#pragma unroll
    for (int r = 0; r < 4; ++r)
#pragma unroll
        for (int c = 0; c < 2; ++c) acco[r][c] = (f32x4)0.f;

    float4 xq[2], scq, shq;
    auto ldx = [&](int cc) {
        int f0 = in_off + cc * 16 + fg * 4;
        scq = *(const float4*)(scA + f0);
        shq = *(const float4*)(shA + f0);
        int gn0 = nblk + n0, gn1 = gn0 + 64;
        xq[0] = (gn0 < N) ? *(const float4*)(xc + (size_t)gn0 * DCAT + f0) : (float4){0.f,0.f,0.f,0.f};
        xq[1] = (gn1 < N) ? *(const float4*)(xc + (size_t)gn1 * DCAT + f0) : (float4){0.f,0.f,0.f,0.f};
    };

    u16x8 pcur[2][4];
    auto phi_compute = [&](int ccc) {
#pragma unroll
        for (int g2 = 0; g2 < 2; ++g2) {
            float xi[4] = {xq[g2].x, xq[g2].y, xq[g2].z, xq[g2].w};
            float scr[4] = {scq.x, scq.y, scq.z, scq.w};
            float shr[4] = {shq.x, shq.y, shq.z, shq.w};
            u16x4 sv;
#pragma unroll
            for (int fl = 0; fl < 4; ++fl) {
                float y = fmaf(xi[fl], scr[fl], shr[fl]);
                // silu side product (for chunk 8)
                sv[fl] = f2bf_rn(silu_f(y));
                float t = (y - g0) * invh;
                float cf = floorf(t);
                int c = (int)cf;
                float u = t - cf;
                float um = 1.f - u;
                float u2 = u * u;
                float um2 = um * um;
                float w0 = um2 * um * (1.f / 6.f);
                float w3 = u2 * u * (1.f / 6.f);
                float w1 = fmaf(fmaf(0.5f, u, -1.f), u2, 2.f / 3.f);
                float w2 = fmaf(fmaf(-0.5f, u, 0.5f), u2, fmaf(0.5f, u, 1.f / 6.f));
                bool e[11];
#pragma unroll
                for (int v = 0; v < 11; ++v) e[v] = (c == v);
#pragma unroll
                for (int s = 0; s < 8; ++s) {
                    float val = 0.f;
                    val = e[s] ? w3 : val;
                    val = e[s + 1] ? w2 : val;
                    val = e[s + 2] ? w1 : val;
                    val = e[s + 3] ? w0 : val;
                    pcur[g2][fl][s] = f2bf_rn(val);
                }
            }
            int gn = nblk + n0 + g2 * 64;
            if (gn < N) {
                int fdst = (ccc * 16 + fg * 4) ^ ((n0 & 7) << 3);
                *(u16x4*)(silbuf + (size_t)gn * 128 + fdst) = sv;
            }
        }
    };

    auto stage_w = [&](int cc) {
        if (CONV) {
            const unsigned short* wcsrc = wconv + (size_t)cc * 128 * 128;
#pragma unroll
            for (int i = 0; i < 8; ++i) {
                int e = tid + i * 256;
                gload_lds16(wcsrc + e * 8, lds_wc + e * 16);
            }
        }
        const unsigned short* wosrc = wout + (size_t)cc * 64 * 128;
#pragma unroll
        for (int i = 0; i < 4; ++i) {
            int e = tid + i * 256;
            gload_lds16(wosrc + e * 8, lds_wo + e * 16);
        }
    };

    auto mfma_phase = [&]() {
#pragma unroll
        for (int kk = 0; kk < 4; ++kk) {
            const int kb = kk * 64 + lg * 16;
            s16x8 af[4];
#pragma unroll
            for (int r = 0; r < 4; ++r) {
                int n = wr * 64 + r * 16 + l15;
                af[r] = *(const s16x8*)(lds_phi + n * 256 + (kb ^ ((n & 7) << 4)));
            }
            if (CONV) {
#pragma unroll
                for (int c = 0; c < 4; ++c) {
                    int o = wc * 64 + c * 16 + l15;
                    s16x8 b = *(const s16x8*)(lds_wc + o * 256 + (kb ^ ((o & 7) << 4)));
#pragma unroll
                    for (int r = 0; r < 4; ++r)
                        accc[r][c] = __builtin_amdgcn_mfma_f32_16x16x32_bf16(af[r], b, accc[r][c], 0, 0, 0);
                }
            }
#pragma unroll
            for (int c = 0; c < 2; ++c) {
                int o = wc * 32 + c * 16 + l15;
                s16x8 b = *(const s16x8*)(lds_wo + o * 256 + (kb ^ ((o & 7) << 4)));
#pragma unroll
                for (int r = 0; r < 4; ++r)
                    acco[r][c] = __builtin_amdgcn_mfma_f32_16x16x32_bf16(af[r], b, acco[r][c], 0, 0, 0);
            }
        }
    };

    // prologue: chunk 0 phi
    ldx(0);
    phi_compute(0);

    for (int cc = 0; cc < 8; ++cc) {
        __syncthreads();                   // prev MFMA done with LDS
        stage_w(cc);                       // async W -> LDS
        // write phi regs -> LDS
#pragma unroll
        for (int g2 = 0; g2 < 2; ++g2) {
            int n = n0 + g2 * 64;
            int swz = (n & 7) << 4;
#pragma unroll
            for (int i = 0; i < 4; ++i) {
                int byte = n * 256 + ((fg * 64 + i * 16) ^ swz);
                *(u16x8*)(lds_phi + byte) = pcur[g2][i];
            }
        }
        __syncthreads();                   // drains vmcnt+lds: W & phi ready
        if (cc < 7) ldx(cc + 1);           // issue next x loads (hidden by MFMA)
        mfma_phase();
        if (cc < 7) phi_compute(cc + 1);   // overlaps MFMA (separate pipes)
    }

    // silu chunk (cc=8): staged back from silbuf, zero VALU
    __syncthreads();                       // also drains this block's silbuf stores
    stage_w(8);
    {
        const unsigned short* ssrc = silbuf + (size_t)nblk * 128;
#pragma unroll
        for (int i = 0; i < 8; ++i) {
            int e = tid + i * 256;
            gload_lds16(ssrc + e * 8, lds_phi + e * 16);
        }
    }
    __syncthreads();
    mfma_phase();

    // epilogue
#pragma unroll
    for (int r = 0; r < 4; ++r) {
        int nb = nblk + wr * 64 + r * 16 + lg * 4;
        if (CONV) {
#pragma unroll
            for (int c = 0; c < 4; ++c) {
                int o = wc * 64 + c * 16 + l15;
#pragma unroll
                for (int q = 0; q < 4; ++q) {
                    int n = nb + q;
                    if (n < N) htmp[(size_t)n * HID + o] = f2bf_rn(accc[r][c][q] * dinv[n]);
                }
            }
        }
#pragma unroll
        for (int c = 0; c < 2; ++c) {
            int o = wc * 32 + c * 16 + l15;
#pragma unroll
            for (int q = 0; q < 4; ++q) {
                int n = nb + q;
                if (n < N) {
                    size_t a = (size_t)n * OOUT + o;
                    float v = acco[r][c][q];
                    if (!INIT) v += out_acc[a];
                    out_acc[a] = v;
                }
            }
        }
    }
}

// ---------------- aggregation (one wave per node; h pre-scaled by dinv) ------
// Edge loop unrolled x4 with independent loads to expose memory-level parallelism.
__global__ __launch_bounds__(256) void agg_kernel(const unsigned short* __restrict__ h,
                                                  const float* __restrict__ dinv,
                                                  const int* __restrict__ offs,
                                                  const int* __restrict__ csr,
                                                  const float* __restrict__ bias,
                                                  float* __restrict__ xc, int out_off, int N) {
    int n = blockIdx.x * 4 + (threadIdx.x >> 6);
    if (n >= N) return;
    int lane = threadIdx.x & 63;
    int s = offs[n], e = offs[n + 1];
    float a0 = 0.f, a1 = 0.f, b0 = 0.f, b1 = 0.f;
    float c0 = 0.f, c1 = 0.f, d0 = 0.f, d1 = 0.f;
    int i = s;
    for (; i + 4 <= e; i += 4) {
        int v0 = csr[i], v1 = csr[i + 1], v2 = csr[i + 2], v3 = csr[i + 3];
        unsigned u0 = *(const unsigned*)(h + (size_t)v0 * HID + lane * 2);
        unsigned u1 = *(const unsigned*)(h + (size_t)v1 * HID + lane * 2);
        unsigned u2 = *(const unsigned*)(h + (size_t)v2 * HID + lane * 2);
        unsigned u3 = *(const unsigned*)(h + (size_t)v3 * HID + lane * 2);
        a0 += __uint_as_float(u0 << 16);
        a1 += __uint_as_float(u0 & 0xffff0000u);
        b0 += __uint_as_float(u1 << 16);
        b1 += __uint_as_float(u1 & 0xffff0000u);
        c0 += __uint_as_float(u2 << 16);
        c1 += __uint_as_float(u2 & 0xffff0000u);
        d0 += __uint_as_float(u3 << 16);
        d1 += __uint_as_float(u3 & 0xffff0000u);
    }
    for (; i < e; ++i) {
        int v = csr[i];
        unsigned u = *(const unsigned*)(h + (size_t)v * HID + lane * 2);
        a0 += __uint_as_float(u << 16);
        a1 += __uint_as_float(u & 0xffff0000u);
    }
    a0 += b0 + c0 + d0;
    a1 += b1 + c1 + d1;
    float dn = dinv[n];
    float2 bv = *(const float2*)(bias + lane * 2);
    float2 res = {fmaf(a0, dn, bv.x), fmaf(a1, dn, bv.y)};
    *(float2*)(xc + (size_t)n * DCAT + out_off + lane * 2) = res;
}

// ---------------- batchnorm stats + deferred affine ----------------
__global__ __launch_bounds__(128) void bn_stats_kernel(const float* __restrict__ xc, int off, int N,
                                                       float* __restrict__ bnsum, float* __restrict__ bnsq) {
    int f = threadIdx.x;
    float s = 0.f, q = 0.f;
    for (int n = blockIdx.x; n < N; n += gridDim.x) {
        float v = xc[(size_t)n * DCAT + off + f];
        s += v;
        q += v * v;
    }
    atomicAdd(&bnsum[f], s);
    atomicAdd(&bnsq[f], q);
}

__global__ __launch_bounds__(128) void bn_affine_kernel(const float* __restrict__ bnsum,
                                                        const float* __restrict__ bnsq,
                                                        const float* __restrict__ gamma,
                                                        const float* __restrict__ beta,
                                                        float* scA, float* shA, int seg_off, float invN) {
    int f = threadIdx.x;
    float mu = bnsum[f] * invN;
    float var = bnsq[f] * invN - mu * mu;
    float rs = rsqrtf(var + 1e-5f);
    float s = gamma[f] * rs;
    scA[seg_off + f] = s;
    shA[seg_off + f] = fmaf(-mu, s, beta[f]);
}

// ---------------- log_softmax (thread per node; reads out_acc ld=64) ---------
__global__ __launch_bounds__(256) void logsoftmax_kernel(const float* __restrict__ oacc,
                                                         float* __restrict__ out, int N) {
    for (int n = blockIdx.x * blockDim.x + threadIdx.x; n < N; n += gridDim.x * blockDim.x) {
        const float* row = oacc + (size_t)n * OOUT;
        float m = -1e30f;
#pragma unroll
        for (int j = 0; j < NCLS; ++j) m = fmaxf(m, row[j]);
        float s = 0.f;
#pragma unroll
        for (int j = 0; j < NCLS; ++j) s += __expf(row[j] - m);
        float lse = m + __logf(s);
        float* orow = out + (size_t)n * NCLS;
#pragma unroll
        for (int j = 0; j < NCLS; ++j) orow[j] = row[j] - lse;
    }
}

// ---------------- launch ----------------

extern "C" void kernel_launch(void* const* d_in, const int* in_sizes, int n_in,
                              void* d_out, int out_size, void* d_ws, size_t ws_size,
                              hipStream_t stream) {
    const float* x            = (const float*)d_in[0];
    const int*   eidx         = (const int*)d_in[1];
    const float* conv_base_w  = (const float*)d_in[3];
    const float* conv_spline_w= (const float*)d_in[4];
    const float* conv_scaler  = (const float*)d_in[5];
    const float* conv_bias    = (const float*)d_in[6];
    const float* bn_gamma     = (const float*)d_in[7];
    const float* bn_beta      = (const float*)d_in[8];
    const float* out_base_w   = (const float*)d_in[10];
    const float* out_spline_w = (const float*)d_in[11];
    const float* out_scaler   = (const float*)d_in[12];
    float* out = (float*)d_out;

    int N = in_sizes[0] / F_IN;
    int E = in_sizes[1] / 2;
    const int* esrc = eidx;
    const int* edst = eidx + E;

    int blocks = (N + 127) / 128;
    int npad = blocks * 128;
    int nsb = (N + 255) / 256;

    char* p = (char*)d_ws;
    auto carve = [&](size_t bytes) {
        char* r = p;
        p += (bytes + 255) & ~(size_t)255;
        return r;
    };
    float* xc   = (float*)carve((size_t)N * DCAT * 4);
    unsigned short* htmp = (unsigned short*)carve((size_t)npad * HID * 2);
    float* oacc = (float*)carve((size_t)npad * OOUT * 4);
    unsigned short* silbuf = (unsigned short*)carve((size_t)npad * 128 * 2);
    float* dinv = (float*)carve((size_t)N * 4);
    float* bn   = (float*)carve((size_t)NLAYER * 2 * HID * 4);
    float* scA  = (float*)carve((size_t)DCAT * 4);
    float* shA  = (float*)carve((size_t)DCAT * 4);
    unsigned short* wpkc = (unsigned short*)carve((size_t)NLAYER * 9 * 128 * 128 * 2);
    unsigned short* wpko = (unsigned short*)carve((size_t)4 * 9 * 64 * 128 * 2);
    int* deg    = (int*)carve((size_t)N * 4);
    int* offs   = (int*)carve((size_t)(N + 1) * 4);
    int* cursor = (int*)carve((size_t)(N + 1) * 4);
    int* bsum   = (int*)carve((size_t)nsb * 4);
    int* bbase  = (int*)carve((size_t)nsb * 4);
    int* csr    = (int*)carve((size_t)(E + N) * 4);

    hipMemsetAsync(bn, 0, NLAYER * 2 * HID * 4, stream);

    // graph preprocessing
    deg_init_kernel<<<512, 256, 0, stream>>>(deg, N);
    deg_count_kernel<<<1024, 256, 0, stream>>>(edst, E, deg);
    dinv_kernel<<<512, 256, 0, stream>>>(deg, dinv, N);
    scan_reduce_kernel<<<nsb, 256, 0, stream>>>(deg, bsum, N);
    scan_top_kernel<<<1, 256, 0, stream>>>(bsum, bbase, nsb);
    scan_write_kernel<<<nsb, 256, 0, stream>>>(deg, bbase, offs, cursor, N);
    fill_kernel<<<1024, 256, 0, stream>>>(esrc, edst, E, N, cursor, csr);

    // weight packing + x copy + affine init
    pack_conv_mfma<<<1024, 256, 0, stream>>>(conv_base_w, conv_spline_w, conv_scaler, wpkc);
    pack_out_mfma<<<1024, 256, 0, stream>>>(out_base_w, out_spline_w, out_scaler, wpko);
    copyx_kernel<<<2048, 256, 0, stream>>>(x, xc, N);
    affine_init_kernel<<<1, 512, 0, stream>>>(scA, shA);

    float invN = 1.f / (float)N;
    for (int l = 0; l < NLAYER; ++l) {
        int in_off = l * HID;
        int out_off = (l + 1) * HID;
        const unsigned short* wl = wpkc + (size_t)l * 9 * 128 * 128;
        const unsigned short* wo = wpko + (size_t)l * 9 * 64 * 128;
        if (l == 0)
            kan_fused_kernel<true, true><<<blocks, 256, 0, stream>>>(
                xc, in_off, scA, shA, wl, wo, silbuf, htmp, dinv, oacc, N);
        else
            kan_fused_kernel<true, false><<<blocks, 256, 0, stream>>>(
                xc, in_off, scA, shA, wl, wo, silbuf, htmp, dinv, oacc, N);
        agg_kernel<<<(N + 3) / 4, 256, 0, stream>>>(htmp, dinv, offs, csr, conv_bias + l * HID, xc, out_off, N);
        float* bnsum = bn + l * 2 * HID;
        float* bnsq  = bnsum + HID;
        bn_stats_kernel<<<256, 128, 0, stream>>>(xc, out_off, N, bnsum, bnsq);
        bn_affine_kernel<<<1, 128, 0, stream>>>(bnsum, bnsq, bn_gamma + l * HID, bn_beta + l * HID,
                                                scA, shA, out_off, invN);
    }

    // segment 3 (final BN output) -> out partial
    kan_fused_kernel<false, false><<<blocks, 256, 0, stream>>>(
        xc, 384, scA, shA, nullptr, wpko + (size_t)3 * 9 * 64 * 128, silbuf, nullptr, dinv, oacc, N);

    logsoftmax_kernel<<<(N + 255) / 256, 256, 0, stream>>>(oacc, out, N);
}